// Round 6
// baseline (783.560 us; speedup 1.0000x reference)
//
#include <hip/hip_runtime.h>
#include <hip/hip_bf16.h>
#include <math.h>

#define N_NODES 20000
#define N_EDGES 320000
#define N_GRAPHS 64

typedef __bf16 bf16_t;
typedef bf16_t bf16x8 __attribute__((ext_vector_type(8)));
typedef bf16_t bf16x4 __attribute__((ext_vector_type(4)));
typedef float f32x4 __attribute__((ext_vector_type(4)));

__device__ __forceinline__ float leaky02(float v) { return v > 0.f ? v : 0.2f * v; }

// ---------------------------------------------------------------- CSR build
__global__ void hist_k(const int* __restrict__ dst, int* __restrict__ deg, int E) {
    int e = blockIdx.x * 256 + threadIdx.x;
    if (e < E) atomicAdd(&deg[dst[e]], 1);
}

__global__ void scan_k(const int* __restrict__ deg, int* __restrict__ offs,
                       int* __restrict__ cursor, int n) {
    __shared__ int buf[1024];
    __shared__ int s_carry;
    int tid = threadIdx.x;
    if (tid == 0) s_carry = 0;
    __syncthreads();
    for (int base = 0; base < n; base += 1024) {
        int carry = s_carry;
        int i = base + tid;
        int v = (i < n) ? deg[i] : 0;
        buf[tid] = v;
        __syncthreads();
        for (int off = 1; off < 1024; off <<= 1) {
            int t = (tid >= off) ? buf[tid - off] : 0;
            __syncthreads();
            buf[tid] += t;
            __syncthreads();
        }
        int incl = buf[tid];
        if (i < n) { int ex = carry + incl - v; offs[i] = ex; cursor[i] = ex; }
        if (tid == 1023) s_carry = carry + incl;
        __syncthreads();
    }
    if (tid == 0) offs[n] = s_carry;
}

__global__ void scatter_k(const int* __restrict__ src, const int* __restrict__ dst,
                          int* __restrict__ cursor, int* __restrict__ csr_src,
                          int* __restrict__ csr_dst, int* __restrict__ csr_eid, int E) {
    int e = blockIdx.x * 256 + threadIdx.x;
    if (e < E) {
        int d = dst[e];
        int p = atomicAdd(&cursor[d], 1);
        csr_src[p] = src[e];
        csr_dst[p] = d;
        csr_eid[p] = e;
    }
}

// --------------------------------------------- weight transpose + bf16 cast
__global__ __launch_bounds__(256) void wt_k(const float* __restrict__ W,
                                            bf16_t* __restrict__ Bt, int K, int N) {
    __shared__ float t[32][33];
    int k0 = blockIdx.y * 32, n0 = blockIdx.x * 32;
    int tx = threadIdx.x & 31, ty = threadIdx.x >> 5;
    for (int i = ty; i < 32; i += 8) t[i][tx] = W[(size_t)(k0 + i) * N + n0 + tx];
    __syncthreads();
    for (int i = ty; i < 32; i += 8)
        Bt[(size_t)(n0 + i) * K + k0 + tx] = (bf16_t)t[tx][i];
}

// ------------------------------------- fold attention vectors into weights
__global__ void fold_k(const float* __restrict__ W, const float* __restrict__ a_s,
                       const float* __restrict__ a_d, float* __restrict__ WaT,
                       int K, int H, int C) {
    int k = blockIdx.x * 64 + threadIdx.x;
    if (k >= K) return;
    int HC = H * C;
    for (int h = 0; h < H; ++h) {
        float s = 0.f, d = 0.f;
        for (int c = 0; c < C; ++c) {
            float w = W[(size_t)k * HC + h * C + c];
            s += w * a_s[h * C + c];
            d += w * a_d[h * C + c];
        }
        WaT[h * K + k] = s;
        WaT[(H + h) * K + k] = d;
    }
}

// ----------------------- prep: layer-1 fused transform matrix [40,256] fp32
__global__ void b1prep_k(const float* __restrict__ W1, const float* __restrict__ lw1,
                         const float* __restrict__ bg, const float* __restrict__ lb,
                         float* __restrict__ B1, float* __restrict__ bb1) {
    int t = threadIdx.x;  // 256, one block
    for (int i = 0; i < 32; ++i) {
        int h = i >> 3, k = i & 7;
        B1[i * 256 + t] = ((t >> 6) == h) ? W1[k * 256 + t] : 0.f;
    }
    for (int k = 0; k < 8; ++k) B1[(32 + k) * 256 + t] = lw1[k * 256 + t];
    bb1[t] = bg[t] + lb[t];
}

// ----------------------- prep: layer-3 fused Bt [128][1792] bf16
__global__ void b3prep_k(const float* __restrict__ W3, const float* __restrict__ lw3,
                         const float* __restrict__ bg, const float* __restrict__ lb,
                         bf16_t* __restrict__ Bt, float* __restrict__ bb) {
    int c = blockIdx.x;  // 0..127
    for (int idx = threadIdx.x; idx < 1792; idx += 256) {
        float v;
        if (idx < 1536) {
            int h = idx >> 8, k = idx & 255;
            v = W3[(size_t)k * 768 + h * 128 + c] * (1.f / 6.f);
        } else {
            int k = idx - 1536;
            v = lw3[(size_t)k * 128 + c];
        }
        Bt[(size_t)c * 1792 + idx] = (bf16_t)v;
    }
    if (threadIdx.x == 0) bb[c] = bg[c] + lb[c];
}

// ---------------------------------------------------------------- fp32 GEMM
template <typename OUT, bool RELU>
__global__ __launch_bounds__(256) void gemm_k(const float* __restrict__ A,
                                              const float* __restrict__ B,
                                              OUT* __restrict__ C,
                                              const float* __restrict__ bias,
                                              int M, int N, int K) {
    __shared__ float As[16][65];
    __shared__ float Bs[16][64];
    int tid = threadIdx.x;
    int tx = tid & 15, ty = tid >> 4;
    int row0 = blockIdx.y * 64, col0 = blockIdx.x * 64;
    float acc[4][4] = {};
    for (int k0 = 0; k0 < K; k0 += 16) {
        #pragma unroll
        for (int i = 0; i < 4; ++i) {
            int idx = tid + i * 256;
            int m = idx >> 4, kk = idx & 15;
            int gm = row0 + m, gk = k0 + kk;
            As[kk][m] = (gm < M && gk < K) ? A[(size_t)gm * K + gk] : 0.f;
        }
        #pragma unroll
        for (int i = 0; i < 4; ++i) {
            int idx = tid + i * 256;
            int kk = idx >> 6, n = idx & 63;
            int gk = k0 + kk, gn = col0 + n;
            Bs[kk][n] = (gk < K && gn < N) ? B[(size_t)gk * N + gn] : 0.f;
        }
        __syncthreads();
        #pragma unroll
        for (int kk = 0; kk < 16; ++kk) {
            float a[4], b[4];
            #pragma unroll
            for (int i = 0; i < 4; ++i) a[i] = As[kk][ty * 4 + i];
            #pragma unroll
            for (int j = 0; j < 4; ++j) b[j] = Bs[kk][tx * 4 + j];
            #pragma unroll
            for (int i = 0; i < 4; ++i)
                #pragma unroll
                for (int j = 0; j < 4; ++j) acc[i][j] += a[i] * b[j];
        }
        __syncthreads();
    }
    #pragma unroll
    for (int i = 0; i < 4; ++i) {
        int gm = row0 + ty * 4 + i;
        if (gm >= M) continue;
        #pragma unroll
        for (int j = 0; j < 4; ++j) {
            int gn = col0 + tx * 4 + j;
            if (gn < N) {
                float v = acc[i][j] + (bias ? bias[gn] : 0.f);
                if (RELU) v = fmaxf(v, 0.f);
                C[(size_t)gm * N + gn] = (OUT)v;
            }
        }
    }
}

// ------------------------------------------------------------ bf16 MFMA GEMM
template <typename OUT, bool RELU>
__global__ __launch_bounds__(256) void gemm_bf16_k(
    const bf16_t* __restrict__ A, const bf16_t* __restrict__ Bt,
    OUT* __restrict__ C, const float* __restrict__ bias, int M, int N, int K) {
    __shared__ bf16_t As[128][40];
    __shared__ bf16_t Bs[128][40];
    int tid = threadIdx.x;
    int row0 = blockIdx.y * 128, col0 = blockIdx.x * 128;
    int wave = tid >> 6, lane = tid & 63, quad = lane >> 4, l16 = lane & 15;
    int wm = wave >> 1, wn = wave & 1;
    f32x4 acc[4][4] = {};
    int sr = tid >> 2;
    int sc = (tid & 3) * 8;
    for (int k0 = 0; k0 < K; k0 += 32) {
        #pragma unroll
        for (int half = 0; half < 2; ++half) {
            int r = sr + half * 64;
            int gm = row0 + r;
            bf16x8 v = {};
            if (gm < M) v = *(const bf16x8*)&A[(size_t)gm * K + k0 + sc];
            *(bf16x8*)&As[r][sc] = v;
            int gn = col0 + r;
            bf16x8 w = {};
            if (gn < N) w = *(const bf16x8*)&Bt[(size_t)gn * K + k0 + sc];
            *(bf16x8*)&Bs[r][sc] = w;
        }
        __syncthreads();
        bf16x8 af[4], bfr[4];
        #pragma unroll
        for (int i = 0; i < 4; ++i) {
            af[i] = *(const bf16x8*)&As[wm * 64 + i * 16 + l16][quad * 8];
            bfr[i] = *(const bf16x8*)&Bs[wn * 64 + i * 16 + l16][quad * 8];
        }
        #pragma unroll
        for (int i = 0; i < 4; ++i)
            #pragma unroll
            for (int j = 0; j < 4; ++j)
                acc[i][j] = __builtin_amdgcn_mfma_f32_16x16x32_bf16(af[i], bfr[j],
                                                                   acc[i][j], 0, 0, 0);
        __syncthreads();
    }
    #pragma unroll
    for (int i = 0; i < 4; ++i) {
        int base_m = row0 + wm * 64 + i * 16 + quad * 4;
        #pragma unroll
        for (int j = 0; j < 4; ++j) {
            int gn = col0 + wn * 64 + j * 16 + l16;
            float bv = bias ? bias[gn] : 0.f;
            #pragma unroll
            for (int r = 0; r < 4; ++r) {
                int gm = base_m + r;
                if (gm < M) {
                    float v = acc[i][j][r] + bv;
                    if (RELU) v = fmaxf(v, 0.f);
                    C[(size_t)gm * N + gn] = (OUT)v;
                }
            }
        }
    }
}

// ------------------------- layer-2 dual GEMM: [Wt2 ‖ lwt2], K=256, N=512
// cols 0..255 -> Ch (bf16, no bias); cols 256..511 -> Cl (f32, +lbias)
__global__ __launch_bounds__(256) void gemm_bf16_dual_k(
    const bf16_t* __restrict__ A, const bf16_t* __restrict__ Bt,
    bf16_t* __restrict__ Ch, float* __restrict__ Cl,
    const float* __restrict__ lbias, int M) {
    const int K = 256;
    __shared__ bf16_t As[128][40];
    __shared__ bf16_t Bs[128][40];
    int tid = threadIdx.x;
    int row0 = blockIdx.y * 128, col0 = blockIdx.x * 128;
    int wave = tid >> 6, lane = tid & 63, quad = lane >> 4, l16 = lane & 15;
    int wm = wave >> 1, wn = wave & 1;
    f32x4 acc[4][4] = {};
    int sr = tid >> 2;
    int sc = (tid & 3) * 8;
    for (int k0 = 0; k0 < K; k0 += 32) {
        #pragma unroll
        for (int half = 0; half < 2; ++half) {
            int r = sr + half * 64;
            int gm = row0 + r;
            bf16x8 v = {};
            if (gm < M) v = *(const bf16x8*)&A[(size_t)gm * K + k0 + sc];
            *(bf16x8*)&As[r][sc] = v;
            int gn = col0 + r;  // < 512 always (grid.x = 4)
            bf16x8 w = *(const bf16x8*)&Bt[(size_t)gn * K + k0 + sc];
            *(bf16x8*)&Bs[r][sc] = w;
        }
        __syncthreads();
        bf16x8 af[4], bfr[4];
        #pragma unroll
        for (int i = 0; i < 4; ++i) {
            af[i] = *(const bf16x8*)&As[wm * 64 + i * 16 + l16][quad * 8];
            bfr[i] = *(const bf16x8*)&Bs[wn * 64 + i * 16 + l16][quad * 8];
        }
        #pragma unroll
        for (int i = 0; i < 4; ++i)
            #pragma unroll
            for (int j = 0; j < 4; ++j)
                acc[i][j] = __builtin_amdgcn_mfma_f32_16x16x32_bf16(af[i], bfr[j],
                                                                   acc[i][j], 0, 0, 0);
        __syncthreads();
    }
    #pragma unroll
    for (int i = 0; i < 4; ++i) {
        int base_m = row0 + wm * 64 + i * 16 + quad * 4;
        #pragma unroll
        for (int j = 0; j < 4; ++j) {
            int gn = col0 + wn * 64 + j * 16 + l16;
            float bv = (gn >= 256) ? lbias[gn - 256] : 0.f;
            #pragma unroll
            for (int r = 0; r < 4; ++r) {
                int gm = base_m + r;
                if (gm < M) {
                    float v = acc[i][j][r] + bv;
                    if (gn < 256) Ch[(size_t)gm * 256 + gn] = (bf16_t)v;
                    else Cl[(size_t)gm * 256 + (gn - 256)] = v;
                }
            }
        }
    }
}

// -------------------------------------------- attention scores via folded W
__global__ void scores1_k(const float* __restrict__ x, const float* __restrict__ WaT,
                          float* __restrict__ as_, float* __restrict__ ad_, int N) {
    int j = blockIdx.x * 256 + threadIdx.x;
    if (j >= N) return;
    float xr[8];
    #pragma unroll
    for (int k = 0; k < 8; ++k) xr[k] = x[(size_t)j * 8 + k];
    #pragma unroll
    for (int t = 0; t < 8; ++t) {
        float s = 0.f;
        #pragma unroll
        for (int k = 0; k < 8; ++k) s += xr[k] * WaT[t * 8 + k];
        if (t < 4) as_[j * 4 + t] = s;
        else ad_[j * 4 + (t - 4)] = s;
    }
}

template <int TWOH>
__global__ __launch_bounds__(256) void scores_k(const bf16_t* __restrict__ xb,
                                                const float* __restrict__ WaT,
                                                float* __restrict__ as_,
                                                float* __restrict__ ad_, int N) {
    int tid = threadIdx.x, wave = tid >> 6, lane = tid & 63;
    int j = blockIdx.x * 4 + wave;
    bf16x4 v = {};
    if (j < N) v = *(const bf16x4*)&xb[(size_t)j * 256 + lane * 4];
    float x0 = (float)v[0], x1 = (float)v[1], x2 = (float)v[2], x3 = (float)v[3];
    float acc[TWOH];
    #pragma unroll
    for (int t = 0; t < TWOH; ++t) {
        f32x4 w = *(const f32x4*)&WaT[t * 256 + lane * 4];
        acc[t] = x0 * w[0] + x1 * w[1] + x2 * w[2] + x3 * w[3];
    }
    #pragma unroll
    for (int off = 32; off; off >>= 1)
        #pragma unroll
        for (int t = 0; t < TWOH; ++t) acc[t] += __shfl_xor(acc[t], off);
    if (lane == 0 && j < N) {
        const int H = TWOH / 2;
        #pragma unroll
        for (int t = 0; t < H; ++t) as_[j * H + t] = acc[t];
        #pragma unroll
        for (int t = 0; t < H; ++t) ad_[j * H + t] = acc[H + t];
    }
}

// ----------------------------- per-edge scores in CSR order (one-time gather)
template <int H>
__global__ void escore_k(const float* __restrict__ as_, const float* __restrict__ ad_,
                         const int* __restrict__ csr_src, const int* __restrict__ csr_dst,
                         float* __restrict__ e_buf, int E) {
    int p = blockIdx.x * 256 + threadIdx.x;
    if (p >= E) return;
    int s = csr_src[p], j = csr_dst[p];
    #pragma unroll
    for (int h = 0; h < H; ++h)
        e_buf[(size_t)p * H + h] = leaky02(as_[s * H + h] + ad_[j * H + h]);
}

// -------------------------- layer-1 x-aggregation (H=4, x 8-wide) -> [N,40]
__global__ __launch_bounds__(256) void agg1_k(
    const float* __restrict__ x, const float* __restrict__ e_buf,
    const int* __restrict__ offs, const int* __restrict__ csr_src,
    float* __restrict__ xagg) {
    int wave = threadIdx.x >> 6, lane = threadIdx.x & 63;
    int j = blockIdx.x * 4 + wave;
    if (j >= N_NODES) return;
    int o0 = offs[j], deg = offs[j + 1] - o0;
    const float* eb = e_buf + (size_t)o0 * 4;
    int nv = deg * 4;
    float lm = -3.4e38f;
    for (int i = lane; i < nv; i += 64) lm = fmaxf(lm, eb[i]);
    #pragma unroll
    for (int off = 4; off < 64; off <<= 1) lm = fmaxf(lm, __shfl_xor(lm, off));
    float ls = 0.f;
    for (int i = lane; i < nv; i += 64) ls += __expf(eb[i] - lm);
    #pragma unroll
    for (int off = 4; off < 64; off <<= 1) ls += __shfl_xor(ls, off);
    int half = lane >> 5, l = lane & 31, h = l >> 3, k = l & 7;
    float m_s = __shfl(lm, h);              // lane h holds head h's max
    float rd_s = 1.f / (__shfl(ls, h) + 1e-16f);
    float acc = 0.f;
    for (int e = half; e < deg; e += 2) {
        int s = csr_src[o0 + e];
        float a = __expf(eb[e * 4 + h] - m_s) * rd_s;
        acc += a * x[(size_t)s * 8 + k];
    }
    acc += __shfl_xor(acc, 32);
    if (lane < 32) xagg[(size_t)j * 40 + lane] = acc;
    else if (lane < 40) xagg[(size_t)j * 40 + lane] = x[(size_t)j * 8 + (lane - 32)];
}

// ------------------------------------------- aggregation, concat (H=4,C=64)
__global__ __launch_bounds__(256) void agg_concat_k(
    const bf16_t* __restrict__ h, const float* __restrict__ e_buf,
    const int* __restrict__ offs, const int* __restrict__ csr_src,
    const float* __restrict__ lin, const float* __restrict__ bgat,
    bf16_t* __restrict__ xb) {
    int j = blockIdx.x;
    int tid = threadIdx.x;  // 256
    int o0 = offs[j], deg = offs[j + 1] - o0;
    const float* eb = e_buf + (size_t)o0 * 4;
    int nv = deg * 4;
    int hme = tid & 3;  // invariant under +=256
    __shared__ float s_part[256];
    __shared__ float s_m[4], s_rd[4];
    __shared__ float s_alpha[64 * 4];
    __shared__ int s_src[64];
    __shared__ float s_red[4][256];
    // max (all threads, contiguous)
    float lm = -3.4e38f;
    for (int i = tid; i < nv; i += 256) lm = fmaxf(lm, eb[i]);
    s_part[tid] = lm;
    __syncthreads();
    if (tid < 4) {
        float m = -3.4e38f;
        for (int t = tid; t < 256; t += 4) m = fmaxf(m, s_part[t]);
        s_m[tid] = m;
    }
    __syncthreads();
    float mh = s_m[hme];
    float ls = 0.f;
    for (int i = tid; i < nv; i += 256) ls += __expf(eb[i] - mh);
    s_part[tid] = ls;
    __syncthreads();
    if (tid < 4) {
        float d = 0.f;
        for (int t = tid; t < 256; t += 4) d += s_part[t];
        s_rd[tid] = 1.f / (d + 1e-16f);
    }
    __syncthreads();
    float rdh = s_rd[hme];
    int slot = tid >> 6;
    int l6 = tid & 63;
    int c0 = l6 * 4;
    int myh = l6 >> 4;
    f32x4 acc = {};
    for (int e0 = 0; e0 < deg; e0 += 64) {
        int ne = min(64, deg - e0);
        if (tid < ne) s_src[tid] = csr_src[o0 + e0 + tid];
        {
            int i = tid;  // ne*4 <= 256: each thread handles at most one i
            if (i < ne * 4) s_alpha[i] = __expf(eb[e0 * 4 + i] - mh) * rdh;
        }
        __syncthreads();
        int e_l = slot;
        for (; e_l + 4 < ne; e_l += 8) {
            int s0 = s_src[e_l], s1 = s_src[e_l + 4];
            float a0 = s_alpha[e_l * 4 + myh], a1 = s_alpha[(e_l + 4) * 4 + myh];
            bf16x4 v0 = *(const bf16x4*)&h[(size_t)s0 * 256 + c0];
            bf16x4 v1 = *(const bf16x4*)&h[(size_t)s1 * 256 + c0];
            #pragma unroll
            for (int i = 0; i < 4; ++i) acc[i] += a0 * (float)v0[i];
            #pragma unroll
            for (int i = 0; i < 4; ++i) acc[i] += a1 * (float)v1[i];
        }
        if (e_l < ne) {
            int s0 = s_src[e_l];
            float a0 = s_alpha[e_l * 4 + myh];
            bf16x4 v0 = *(const bf16x4*)&h[(size_t)s0 * 256 + c0];
            #pragma unroll
            for (int i = 0; i < 4; ++i) acc[i] += a0 * (float)v0[i];
        }
        __syncthreads();
    }
    #pragma unroll
    for (int i = 0; i < 4; ++i) s_red[slot][c0 + i] = acc[i];
    __syncthreads();
    if (tid < 64) {
        f32x4 r0 = *(const f32x4*)&s_red[0][c0];
        f32x4 r1 = *(const f32x4*)&s_red[1][c0];
        f32x4 r2 = *(const f32x4*)&s_red[2][c0];
        f32x4 r3 = *(const f32x4*)&s_red[3][c0];
        f32x4 bg = *(const f32x4*)&bgat[c0];
        f32x4 ln = *(const f32x4*)&lin[(size_t)j * 256 + c0];
        bf16x4 o;
        #pragma unroll
        for (int i = 0; i < 4; ++i) {
            float v = fmaxf(r0[i] + r1[i] + r2[i] + r3[i] + bg[i] + ln[i], 0.f);
            o[i] = (bf16_t)v;
        }
        *(bf16x4*)&xb[(size_t)j * 256 + c0] = o;
    }
}

// ------------------- layer-3 x-aggregation (H=6 over x2 [N,256]) + att write
__global__ __launch_bounds__(256) void agg3_k(
    const bf16_t* __restrict__ x2, const float* __restrict__ e_buf,
    const int* __restrict__ offs, const int* __restrict__ csr_src,
    const int* __restrict__ csr_eid, bf16_t* __restrict__ xagg,
    float* __restrict__ att) {
    int j = blockIdx.x;
    int tid = threadIdx.x;  // 256
    int o0 = offs[j], deg = offs[j + 1] - o0;
    const float* eb = e_buf + (size_t)o0 * 6;
    int nv = deg * 6;
    int hm = tid % 6;  // invariant under +=252 (for tid<252)
    __shared__ float s_part[252];
    __shared__ float s_m[6], s_rd[6];
    __shared__ float s_alpha[64 * 6];
    __shared__ int s_src[64];
    __shared__ float s_red[4][6 * 256];  // 24 KB
    // max
    float lm = -3.4e38f;
    if (tid < 252) {
        for (int i = tid; i < nv; i += 252) lm = fmaxf(lm, eb[i]);
        s_part[tid] = lm;
    }
    __syncthreads();
    if (tid < 6) {
        float m = -3.4e38f;
        for (int t = tid; t < 252; t += 6) m = fmaxf(m, s_part[t]);
        s_m[tid] = m;
    }
    __syncthreads();
    float mh = 0.f, ls = 0.f;
    if (tid < 252) {
        mh = s_m[hm];
        for (int i = tid; i < nv; i += 252) ls += __expf(eb[i] - mh);
        s_part[tid] = ls;
    }
    __syncthreads();
    if (tid < 6) {
        float d = 0.f;
        for (int t = tid; t < 252; t += 6) d += s_part[t];
        s_rd[tid] = 1.f / (d + 1e-16f);
    }
    __syncthreads();
    float rdh = (tid < 252) ? s_rd[hm] : 0.f;
    int slot = tid >> 6;
    int c0 = (tid & 63) * 4;
    f32x4 acc[6] = {};
    for (int e0 = 0; e0 < deg; e0 += 64) {
        int ne = min(64, deg - e0);
        if (tid < ne) s_src[tid] = csr_src[o0 + e0 + tid];
        if (tid < 252) {
            for (int i = tid; i < ne * 6; i += 252) {
                float al = __expf(eb[e0 * 6 + i] - mh) * rdh;
                s_alpha[i] = al;
                int e_l = i / 6;
                att[(size_t)csr_eid[o0 + e0 + e_l] * 6 + hm] = al;
            }
        }
        __syncthreads();
        for (int e_l = slot; e_l < ne; e_l += 4) {
            int s = s_src[e_l];
            bf16x4 v = *(const bf16x4*)&x2[(size_t)s * 256 + c0];
            float f0 = (float)v[0], f1 = (float)v[1], f2 = (float)v[2], f3 = (float)v[3];
            #pragma unroll
            for (int hh = 0; hh < 6; ++hh) {
                float a = s_alpha[e_l * 6 + hh];
                acc[hh][0] += a * f0;
                acc[hh][1] += a * f1;
                acc[hh][2] += a * f2;
                acc[hh][3] += a * f3;
            }
        }
        __syncthreads();
    }
    #pragma unroll
    for (int hh = 0; hh < 6; ++hh) *(f32x4*)&s_red[slot][hh * 256 + c0] = acc[hh];
    __syncthreads();
    bf16_t* row = xagg + (size_t)j * 1792;
    #pragma unroll
    for (int hh = 0; hh < 6; ++hh) {
        int idx = hh * 256 + tid;
        float s = s_red[0][idx] + s_red[1][idx] + s_red[2][idx] + s_red[3][idx];
        row[idx] = (bf16_t)s;
    }
    row[1536 + tid] = x2[(size_t)j * 256 + tid];
}

// ---------------------------------------------------------------- BatchNorm
__global__ void bn_stats_k(const float* __restrict__ y, float* __restrict__ sums, int N) {
    int c = threadIdx.x;  // 128
    float s = 0.f, q = 0.f;
    for (int r = blockIdx.x; r < N; r += gridDim.x) {
        float v = y[(size_t)r * 128 + c];
        s += v;
        q += v * v;
    }
    atomicAdd(&sums[c], s);
    atomicAdd(&sums[128 + c], q);
}
__global__ void bn_scale_k(const float* __restrict__ sums, const float* __restrict__ gamma,
                           const float* __restrict__ beta, float* __restrict__ scale,
                           float* __restrict__ shift, int N) {
    int c = threadIdx.x;
    float mu = sums[c] / (float)N;
    float var = fmaxf(sums[128 + c] / (float)N - mu * mu, 0.f);
    float inv = rsqrtf(var + 1e-5f) * gamma[c];
    scale[c] = inv;
    shift[c] = beta[c] - mu * inv;
}

// ---------------------------------------------------------------- max pool
__device__ __forceinline__ unsigned f2key(float f) {
    unsigned b = __float_as_uint(f);
    return (b & 0x80000000u) ? ~b : (b | 0x80000000u);
}
__global__ void pool_init_k(unsigned* __restrict__ pool_u) {
    int i = blockIdx.x * 256 + threadIdx.x;
    if (i < N_GRAPHS * 128) pool_u[i] = f2key(-3.402823466e38f * 2.0f);
}
__global__ void norm_pool_k(const float* __restrict__ y, const float* __restrict__ scale,
                            const float* __restrict__ shift, const int* __restrict__ batch,
                            unsigned* __restrict__ pool_u, int N) {
    int idx = blockIdx.x * 256 + threadIdx.x;
    if (idx >= N * 128) return;
    int n = idx >> 7, c = idx & 127;
    float v = y[idx] * scale[c] + shift[c];
    atomicMax(&pool_u[batch[n] * 128 + c], f2key(v));
}
__global__ void pool_write_k(const unsigned* __restrict__ pool_u, float* __restrict__ out) {
    int i = blockIdx.x * 256 + threadIdx.x;
    if (i < N_GRAPHS * 128) {
        unsigned u = pool_u[i];
        unsigned b = (u & 0x80000000u) ? (u & 0x7FFFFFFFu) : ~u;
        out[i] = __uint_as_float(b);
    }
}

// ================================================================ launcher
extern "C" void kernel_launch(void* const* d_in, const int* in_sizes, int n_in,
                              void* d_out, int out_size, void* d_ws, size_t ws_size,
                              hipStream_t stream) {
    const int N = N_NODES, E = N_EDGES;
    const float* x_ppi = (const float*)d_in[0];
    const int* edge = (const int*)d_in[1];
    const int* batch = (const int*)d_in[2];
    const float* W1 = (const float*)d_in[3];
    const float* a_src1 = (const float*)d_in[4];
    const float* a_dst1 = (const float*)d_in[5];
    const float* b_gat1 = (const float*)d_in[6];
    const float* lw1 = (const float*)d_in[7];
    const float* lb1 = (const float*)d_in[8];
    const float* W2 = (const float*)d_in[9];
    const float* a_src2 = (const float*)d_in[10];
    const float* a_dst2 = (const float*)d_in[11];
    const float* b_gat2 = (const float*)d_in[12];
    const float* lw2 = (const float*)d_in[13];
    const float* lb2 = (const float*)d_in[14];
    const float* W3 = (const float*)d_in[15];
    const float* a_src3 = (const float*)d_in[16];
    const float* a_dst3 = (const float*)d_in[17];
    const float* b_gat3 = (const float*)d_in[18];
    const float* lw3 = (const float*)d_in[19];
    const float* lb3 = (const float*)d_in[20];
    const float* bn_gamma = (const float*)d_in[21];
    const float* bn_beta = (const float*)d_in[22];

    const int* src = edge;
    const int* dst = edge + E;

    size_t off = 0;
    auto alloc = [&](size_t bytes) {
        size_t o = off;
        off = (off + bytes + 255) & ~(size_t)255;
        return o;
    };
    char* ws = (char*)d_ws;
    bf16_t* xb = (bf16_t*)(ws + alloc((size_t)N * 256 * 2));
    // big region: xagg3 [N,1792] bf16; hb and lin alias its front (dead before
    // agg3_k writes xagg3)
    char* bigA = ws + alloc((size_t)N * 1792 * 2);
    bf16_t* xagg3 = (bf16_t*)bigA;
    bf16_t* hb = (bf16_t*)bigA;                                  // [N,256] bf16
    float* lin = (float*)(bigA + (((size_t)N * 256 * 2 + 255) & ~(size_t)255));
    float* xagg1 = (float*)(ws + alloc((size_t)N * 40 * 4));
    float* y = (float*)(ws + alloc((size_t)N * 128 * 4));
    float* as_ = (float*)(ws + alloc((size_t)N * 6 * 4));
    float* ad_ = (float*)(ws + alloc((size_t)N * 6 * 4));
    int* deg = (int*)(ws + alloc((size_t)(N + 1) * 4));
    int* offs = (int*)(ws + alloc((size_t)(N + 1) * 4));
    int* cursor = (int*)(ws + alloc((size_t)(N + 1) * 4));
    int* csr_src = (int*)(ws + alloc((size_t)E * 4));
    int* csr_dst = (int*)(ws + alloc((size_t)E * 4));
    int* csr_eid = (int*)(ws + alloc((size_t)E * 4));
    float* e_buf = (float*)(ws + alloc((size_t)E * 6 * 4));
    bf16_t* Bt2c = (bf16_t*)(ws + alloc((size_t)512 * 256 * 2));
    bf16_t* Bt3x = (bf16_t*)(ws + alloc((size_t)128 * 1792 * 2));
    float* B1 = (float*)(ws + alloc((size_t)40 * 256 * 4));
    float* bb1 = (float*)(ws + alloc(256 * 4));
    float* bb3 = (float*)(ws + alloc(128 * 4));
    float* WaT1 = (float*)(ws + alloc(64 * 4));
    float* WaT2 = (float*)(ws + alloc(2048 * 4));
    float* WaT3 = (float*)(ws + alloc(3072 * 4));
    float* bn_sums = (float*)(ws + alloc(256 * 4));
    float* bn_scale = (float*)(ws + alloc(128 * 4));
    float* bn_shift = (float*)(ws + alloc(128 * 4));
    unsigned* pool_u = (unsigned*)(ws + alloc((size_t)N_GRAPHS * 128 * 4));

    float* out_pool = (float*)d_out;
    float* out_att = (float*)d_out + N_GRAPHS * 128;

    // ---- CSR + weight prep (independent)
    hipMemsetAsync(deg, 0, (size_t)N * 4, stream);
    hist_k<<<(E + 255) / 256, 256, 0, stream>>>(dst, deg, E);
    scan_k<<<1, 1024, 0, stream>>>(deg, offs, cursor, N);
    scatter_k<<<(E + 255) / 256, 256, 0, stream>>>(src, dst, cursor, csr_src, csr_dst,
                                                   csr_eid, E);
    wt_k<<<dim3(8, 8), 256, 0, stream>>>(W2, Bt2c, 256, 256);
    wt_k<<<dim3(8, 8), 256, 0, stream>>>(lw2, Bt2c + 256 * 256, 256, 256);
    fold_k<<<1, 64, 0, stream>>>(W1, a_src1, a_dst1, WaT1, 8, 4, 64);
    fold_k<<<4, 64, 0, stream>>>(W2, a_src2, a_dst2, WaT2, 256, 4, 64);
    fold_k<<<4, 64, 0, stream>>>(W3, a_src3, a_dst3, WaT3, 256, 6, 128);
    b1prep_k<<<1, 256, 0, stream>>>(W1, lw1, b_gat1, lb1, B1, bb1);
    b3prep_k<<<128, 256, 0, stream>>>(W3, lw3, b_gat3, lb3, Bt3x, bb3);

    // ---- Layer 1: scores from x, edge scores, aggregate x, one fused GEMM
    scores1_k<<<(N + 255) / 256, 256, 0, stream>>>(x_ppi, WaT1, as_, ad_, N);
    escore_k<4><<<(E + 255) / 256, 256, 0, stream>>>(as_, ad_, csr_src, csr_dst, e_buf, E);
    agg1_k<<<(N + 3) / 4, 256, 0, stream>>>(x_ppi, e_buf, offs, csr_src, xagg1);
    gemm_k<bf16_t, true><<<dim3(4, 313), 256, 0, stream>>>(xagg1, B1, xb, bb1, N, 256, 40);

    // ---- Layer 2 (256 -> 256, dual-output bf16 MFMA GEMM)
    gemm_bf16_dual_k<<<dim3(4, 157), 256, 0, stream>>>(xb, Bt2c, hb, lin, lb2, N);
    scores_k<8><<<(N + 3) / 4, 256, 0, stream>>>(xb, WaT2, as_, ad_, N);
    escore_k<4><<<(E + 255) / 256, 256, 0, stream>>>(as_, ad_, csr_src, csr_dst, e_buf, E);
    agg_concat_k<<<N, 256, 0, stream>>>(hb, e_buf, offs, csr_src, lin, b_gat2, xb);

    // ---- Layer 3: scores, edge scores, aggregate x2 per head (+att), GEMM
    scores_k<12><<<(N + 3) / 4, 256, 0, stream>>>(xb, WaT3, as_, ad_, N);
    escore_k<6><<<(E + 255) / 256, 256, 0, stream>>>(as_, ad_, csr_src, csr_dst, e_buf, E);
    agg3_k<<<N, 256, 0, stream>>>(xb, e_buf, offs, csr_src, csr_eid, xagg3, out_att);
    gemm_bf16_k<float, true><<<dim3(1, 157), 256, 0, stream>>>(xagg3, Bt3x, y, bb3,
                                                               N, 128, 1792);

    // ---- BatchNorm (training stats, fused sum+sumsq pass)
    hipMemsetAsync(bn_sums, 0, 256 * 4, stream);
    bn_stats_k<<<160, 128, 0, stream>>>(y, bn_sums, N);
    bn_scale_k<<<1, 128, 0, stream>>>(bn_sums, bn_gamma, bn_beta, bn_scale, bn_shift, N);

    // ---- normalize + global max pool
    pool_init_k<<<(N_GRAPHS * 128 + 255) / 256, 256, 0, stream>>>(pool_u);
    norm_pool_k<<<((size_t)N * 128 + 255) / 256, 256, 0, stream>>>(y, bn_scale, bn_shift, batch,
                                                                   pool_u, N);
    pool_write_k<<<(N_GRAPHS * 128 + 255) / 256, 256, 0, stream>>>(pool_u, out_pool);
}

// Round 7
// 730.356 us; speedup vs baseline: 1.0728x; 1.0728x over previous
//
#include <hip/hip_runtime.h>
#include <hip/hip_bf16.h>
#include <math.h>

#define N_NODES 20000
#define N_EDGES 320000
#define N_GRAPHS 64

typedef __bf16 bf16_t;
typedef bf16_t bf16x8 __attribute__((ext_vector_type(8)));
typedef bf16_t bf16x4 __attribute__((ext_vector_type(4)));
typedef float f32x4 __attribute__((ext_vector_type(4)));

__device__ __forceinline__ float leaky02(float v) { return v > 0.f ? v : 0.2f * v; }

// ---------------------------------------------------------------- CSR build
__global__ void hist_k(const int* __restrict__ dst, int* __restrict__ deg, int E) {
    int e = blockIdx.x * 256 + threadIdx.x;
    if (e < E) atomicAdd(&deg[dst[e]], 1);
}

__global__ void scan_k(const int* __restrict__ deg, int* __restrict__ offs,
                       int* __restrict__ cursor, int n) {
    __shared__ int buf[1024];
    __shared__ int s_carry;
    int tid = threadIdx.x;
    if (tid == 0) s_carry = 0;
    __syncthreads();
    for (int base = 0; base < n; base += 1024) {
        int carry = s_carry;
        int i = base + tid;
        int v = (i < n) ? deg[i] : 0;
        buf[tid] = v;
        __syncthreads();
        for (int off = 1; off < 1024; off <<= 1) {
            int t = (tid >= off) ? buf[tid - off] : 0;
            __syncthreads();
            buf[tid] += t;
            __syncthreads();
        }
        int incl = buf[tid];
        if (i < n) { int ex = carry + incl - v; offs[i] = ex; cursor[i] = ex; }
        if (tid == 1023) s_carry = carry + incl;
        __syncthreads();
    }
    if (tid == 0) offs[n] = s_carry;
}

__global__ void scatter_k(const int* __restrict__ src, const int* __restrict__ dst,
                          int* __restrict__ cursor, int* __restrict__ csr_src,
                          int* __restrict__ csr_dst, int* __restrict__ csr_eid, int E) {
    int e = blockIdx.x * 256 + threadIdx.x;
    if (e < E) {
        int d = dst[e];
        int p = atomicAdd(&cursor[d], 1);
        csr_src[p] = src[e];
        csr_dst[p] = d;
        csr_eid[p] = e;
    }
}

// --------------------------------------------- weight transpose + bf16 cast
__global__ __launch_bounds__(256) void wt_k(const float* __restrict__ W,
                                            bf16_t* __restrict__ Bt, int K, int N) {
    __shared__ float t[32][33];
    int k0 = blockIdx.y * 32, n0 = blockIdx.x * 32;
    int tx = threadIdx.x & 31, ty = threadIdx.x >> 5;
    for (int i = ty; i < 32; i += 8) t[i][tx] = W[(size_t)(k0 + i) * N + n0 + tx];
    __syncthreads();
    for (int i = ty; i < 32; i += 8)
        Bt[(size_t)(n0 + i) * K + k0 + tx] = (bf16_t)t[tx][i];
}

// ------------------------------------- fold attention vectors into weights
__global__ void fold_k(const float* __restrict__ W, const float* __restrict__ a_s,
                       const float* __restrict__ a_d, float* __restrict__ WaT,
                       int K, int H, int C) {
    int k = blockIdx.x * 64 + threadIdx.x;
    if (k >= K) return;
    int HC = H * C;
    for (int h = 0; h < H; ++h) {
        float s = 0.f, d = 0.f;
        for (int c = 0; c < C; ++c) {
            float w = W[(size_t)k * HC + h * C + c];
            s += w * a_s[h * C + c];
            d += w * a_d[h * C + c];
        }
        WaT[h * K + k] = s;
        WaT[(H + h) * K + k] = d;
    }
}

// ----------------------- prep: layer-1 fused transform matrix [40,256] fp32
__global__ void b1prep_k(const float* __restrict__ W1, const float* __restrict__ lw1,
                         const float* __restrict__ bg, const float* __restrict__ lb,
                         float* __restrict__ B1, float* __restrict__ bb1) {
    int t = threadIdx.x;  // 256, one block
    for (int i = 0; i < 32; ++i) {
        int h = i >> 3, k = i & 7;
        B1[i * 256 + t] = ((t >> 6) == h) ? W1[k * 256 + t] : 0.f;
    }
    for (int k = 0; k < 8; ++k) B1[(32 + k) * 256 + t] = lw1[k * 256 + t];
    bb1[t] = bg[t] + lb[t];
}

// ----------------------- prep: layer-3 fused Bt [128][1792] bf16
__global__ void b3prep_k(const float* __restrict__ W3, const float* __restrict__ lw3,
                         const float* __restrict__ bg, const float* __restrict__ lb,
                         bf16_t* __restrict__ Bt, float* __restrict__ bb) {
    int c = blockIdx.x;  // 0..127
    for (int idx = threadIdx.x; idx < 1792; idx += 256) {
        float v;
        if (idx < 1536) {
            int h = idx >> 8, k = idx & 255;
            v = W3[(size_t)k * 768 + h * 128 + c] * (1.f / 6.f);
        } else {
            int k = idx - 1536;
            v = lw3[(size_t)k * 128 + c];
        }
        Bt[(size_t)c * 1792 + idx] = (bf16_t)v;
    }
    if (threadIdx.x == 0) bb[c] = bg[c] + lb[c];
}

// ---------------------------------------------------------------- fp32 GEMM
template <typename OUT, bool RELU>
__global__ __launch_bounds__(256) void gemm_k(const float* __restrict__ A,
                                              const float* __restrict__ B,
                                              OUT* __restrict__ C,
                                              const float* __restrict__ bias,
                                              int M, int N, int K) {
    __shared__ float As[16][65];
    __shared__ float Bs[16][64];
    int tid = threadIdx.x;
    int tx = tid & 15, ty = tid >> 4;
    int row0 = blockIdx.y * 64, col0 = blockIdx.x * 64;
    float acc[4][4] = {};
    for (int k0 = 0; k0 < K; k0 += 16) {
        #pragma unroll
        for (int i = 0; i < 4; ++i) {
            int idx = tid + i * 256;
            int m = idx >> 4, kk = idx & 15;
            int gm = row0 + m, gk = k0 + kk;
            As[kk][m] = (gm < M && gk < K) ? A[(size_t)gm * K + gk] : 0.f;
        }
        #pragma unroll
        for (int i = 0; i < 4; ++i) {
            int idx = tid + i * 256;
            int kk = idx >> 6, n = idx & 63;
            int gk = k0 + kk, gn = col0 + n;
            Bs[kk][n] = (gk < K && gn < N) ? B[(size_t)gk * N + gn] : 0.f;
        }
        __syncthreads();
        #pragma unroll
        for (int kk = 0; kk < 16; ++kk) {
            float a[4], b[4];
            #pragma unroll
            for (int i = 0; i < 4; ++i) a[i] = As[kk][ty * 4 + i];
            #pragma unroll
            for (int j = 0; j < 4; ++j) b[j] = Bs[kk][tx * 4 + j];
            #pragma unroll
            for (int i = 0; i < 4; ++i)
                #pragma unroll
                for (int j = 0; j < 4; ++j) acc[i][j] += a[i] * b[j];
        }
        __syncthreads();
    }
    #pragma unroll
    for (int i = 0; i < 4; ++i) {
        int gm = row0 + ty * 4 + i;
        if (gm >= M) continue;
        #pragma unroll
        for (int j = 0; j < 4; ++j) {
            int gn = col0 + tx * 4 + j;
            if (gn < N) {
                float v = acc[i][j] + (bias ? bias[gn] : 0.f);
                if (RELU) v = fmaxf(v, 0.f);
                C[(size_t)gm * N + gn] = (OUT)v;
            }
        }
    }
}

// ------------------------------------------------------------ bf16 MFMA GEMM
template <typename OUT, bool RELU>
__global__ __launch_bounds__(256) void gemm_bf16_k(
    const bf16_t* __restrict__ A, const bf16_t* __restrict__ Bt,
    OUT* __restrict__ C, const float* __restrict__ bias, int M, int N, int K) {
    __shared__ bf16_t As[128][40];
    __shared__ bf16_t Bs[128][40];
    int tid = threadIdx.x;
    int row0 = blockIdx.y * 128, col0 = blockIdx.x * 128;
    int wave = tid >> 6, lane = tid & 63, quad = lane >> 4, l16 = lane & 15;
    int wm = wave >> 1, wn = wave & 1;
    f32x4 acc[4][4] = {};
    int sr = tid >> 2;
    int sc = (tid & 3) * 8;
    for (int k0 = 0; k0 < K; k0 += 32) {
        #pragma unroll
        for (int half = 0; half < 2; ++half) {
            int r = sr + half * 64;
            int gm = row0 + r;
            bf16x8 v = {};
            if (gm < M) v = *(const bf16x8*)&A[(size_t)gm * K + k0 + sc];
            *(bf16x8*)&As[r][sc] = v;
            int gn = col0 + r;
            bf16x8 w = {};
            if (gn < N) w = *(const bf16x8*)&Bt[(size_t)gn * K + k0 + sc];
            *(bf16x8*)&Bs[r][sc] = w;
        }
        __syncthreads();
        bf16x8 af[4], bfr[4];
        #pragma unroll
        for (int i = 0; i < 4; ++i) {
            af[i] = *(const bf16x8*)&As[wm * 64 + i * 16 + l16][quad * 8];
            bfr[i] = *(const bf16x8*)&Bs[wn * 64 + i * 16 + l16][quad * 8];
        }
        #pragma unroll
        for (int i = 0; i < 4; ++i)
            #pragma unroll
            for (int j = 0; j < 4; ++j)
                acc[i][j] = __builtin_amdgcn_mfma_f32_16x16x32_bf16(af[i], bfr[j],
                                                                   acc[i][j], 0, 0, 0);
        __syncthreads();
    }
    #pragma unroll
    for (int i = 0; i < 4; ++i) {
        int base_m = row0 + wm * 64 + i * 16 + quad * 4;
        #pragma unroll
        for (int j = 0; j < 4; ++j) {
            int gn = col0 + wn * 64 + j * 16 + l16;
            float bv = bias ? bias[gn] : 0.f;
            #pragma unroll
            for (int r = 0; r < 4; ++r) {
                int gm = base_m + r;
                if (gm < M) {
                    float v = acc[i][j][r] + bv;
                    if (RELU) v = fmaxf(v, 0.f);
                    C[(size_t)gm * N + gn] = (OUT)v;
                }
            }
        }
    }
}

// ------------------------- layer-2 dual GEMM: [Wt2 ‖ lwt2], K=256, N=512
__global__ __launch_bounds__(256) void gemm_bf16_dual_k(
    const bf16_t* __restrict__ A, const bf16_t* __restrict__ Bt,
    bf16_t* __restrict__ Ch, float* __restrict__ Cl,
    const float* __restrict__ lbias, int M) {
    const int K = 256;
    __shared__ bf16_t As[128][40];
    __shared__ bf16_t Bs[128][40];
    int tid = threadIdx.x;
    int row0 = blockIdx.y * 128, col0 = blockIdx.x * 128;
    int wave = tid >> 6, lane = tid & 63, quad = lane >> 4, l16 = lane & 15;
    int wm = wave >> 1, wn = wave & 1;
    f32x4 acc[4][4] = {};
    int sr = tid >> 2;
    int sc = (tid & 3) * 8;
    for (int k0 = 0; k0 < K; k0 += 32) {
        #pragma unroll
        for (int half = 0; half < 2; ++half) {
            int r = sr + half * 64;
            int gm = row0 + r;
            bf16x8 v = {};
            if (gm < M) v = *(const bf16x8*)&A[(size_t)gm * K + k0 + sc];
            *(bf16x8*)&As[r][sc] = v;
            int gn = col0 + r;  // < 512 always (grid.x = 4)
            bf16x8 w = *(const bf16x8*)&Bt[(size_t)gn * K + k0 + sc];
            *(bf16x8*)&Bs[r][sc] = w;
        }
        __syncthreads();
        bf16x8 af[4], bfr[4];
        #pragma unroll
        for (int i = 0; i < 4; ++i) {
            af[i] = *(const bf16x8*)&As[wm * 64 + i * 16 + l16][quad * 8];
            bfr[i] = *(const bf16x8*)&Bs[wn * 64 + i * 16 + l16][quad * 8];
        }
        #pragma unroll
        for (int i = 0; i < 4; ++i)
            #pragma unroll
            for (int j = 0; j < 4; ++j)
                acc[i][j] = __builtin_amdgcn_mfma_f32_16x16x32_bf16(af[i], bfr[j],
                                                                   acc[i][j], 0, 0, 0);
        __syncthreads();
    }
    #pragma unroll
    for (int i = 0; i < 4; ++i) {
        int base_m = row0 + wm * 64 + i * 16 + quad * 4;
        #pragma unroll
        for (int j = 0; j < 4; ++j) {
            int gn = col0 + wn * 64 + j * 16 + l16;
            float bv = (gn >= 256) ? lbias[gn - 256] : 0.f;
            #pragma unroll
            for (int r = 0; r < 4; ++r) {
                int gm = base_m + r;
                if (gm < M) {
                    float v = acc[i][j][r] + bv;
                    if (gn < 256) Ch[(size_t)gm * 256 + gn] = (bf16_t)v;
                    else Cl[(size_t)gm * 256 + (gn - 256)] = v;
                }
            }
        }
    }
}

// -------------------------------------------- attention scores via folded W
__global__ void scores1_k(const float* __restrict__ x, const float* __restrict__ WaT,
                          float* __restrict__ as_, float* __restrict__ ad_, int N) {
    int j = blockIdx.x * 256 + threadIdx.x;
    if (j >= N) return;
    float xr[8];
    #pragma unroll
    for (int k = 0; k < 8; ++k) xr[k] = x[(size_t)j * 8 + k];
    #pragma unroll
    for (int t = 0; t < 8; ++t) {
        float s = 0.f;
        #pragma unroll
        for (int k = 0; k < 8; ++k) s += xr[k] * WaT[t * 8 + k];
        if (t < 4) as_[j * 4 + t] = s;
        else ad_[j * 4 + (t - 4)] = s;
    }
}

template <int TWOH>
__global__ __launch_bounds__(256) void scores_k(const bf16_t* __restrict__ xb,
                                                const float* __restrict__ WaT,
                                                float* __restrict__ as_,
                                                float* __restrict__ ad_, int N) {
    int tid = threadIdx.x, wave = tid >> 6, lane = tid & 63;
    int j = blockIdx.x * 4 + wave;
    bf16x4 v = {};
    if (j < N) v = *(const bf16x4*)&xb[(size_t)j * 256 + lane * 4];
    float x0 = (float)v[0], x1 = (float)v[1], x2 = (float)v[2], x3 = (float)v[3];
    float acc[TWOH];
    #pragma unroll
    for (int t = 0; t < TWOH; ++t) {
        f32x4 w = *(const f32x4*)&WaT[t * 256 + lane * 4];
        acc[t] = x0 * w[0] + x1 * w[1] + x2 * w[2] + x3 * w[3];
    }
    #pragma unroll
    for (int off = 32; off; off >>= 1)
        #pragma unroll
        for (int t = 0; t < TWOH; ++t) acc[t] += __shfl_xor(acc[t], off);
    if (lane == 0 && j < N) {
        const int H = TWOH / 2;
        #pragma unroll
        for (int t = 0; t < H; ++t) as_[j * H + t] = acc[t];
        #pragma unroll
        for (int t = 0; t < H; ++t) ad_[j * H + t] = acc[H + t];
    }
}

// ----------------------------- per-edge scores in CSR order (one-time gather)
template <int H>
__global__ void escore_k(const float* __restrict__ as_, const float* __restrict__ ad_,
                         const int* __restrict__ csr_src, const int* __restrict__ csr_dst,
                         float* __restrict__ e_buf, int E) {
    int p = blockIdx.x * 256 + threadIdx.x;
    if (p >= E) return;
    int s = csr_src[p], j = csr_dst[p];
    #pragma unroll
    for (int h = 0; h < H; ++h)
        e_buf[(size_t)p * H + h] = leaky02(as_[s * H + h] + ad_[j * H + h]);
}

// -------------------------- layer-1 x-aggregation (H=4, x 8-wide) -> [N,40]
__global__ __launch_bounds__(256) void agg1_k(
    const float* __restrict__ x, const float* __restrict__ e_buf,
    const int* __restrict__ offs, const int* __restrict__ csr_src,
    float* __restrict__ xagg) {
    int wave = threadIdx.x >> 6, lane = threadIdx.x & 63;
    int j = blockIdx.x * 4 + wave;
    if (j >= N_NODES) return;
    int o0 = offs[j], deg = offs[j + 1] - o0;
    const float* eb = e_buf + (size_t)o0 * 4;
    int nv = deg * 4;
    float lm = -3.4e38f;
    for (int i = lane; i < nv; i += 64) lm = fmaxf(lm, eb[i]);
    #pragma unroll
    for (int off = 4; off < 64; off <<= 1) lm = fmaxf(lm, __shfl_xor(lm, off));
    float ls = 0.f;
    for (int i = lane; i < nv; i += 64) ls += __expf(eb[i] - lm);
    #pragma unroll
    for (int off = 4; off < 64; off <<= 1) ls += __shfl_xor(ls, off);
    int half = lane >> 5, l = lane & 31, h = l >> 3, k = l & 7;
    float m_s = __shfl(lm, h);
    float rd_s = 1.f / (__shfl(ls, h) + 1e-16f);
    float acc = 0.f;
    for (int e = half; e < deg; e += 2) {
        int s = csr_src[o0 + e];
        float a = __expf(eb[e * 4 + h] - m_s) * rd_s;
        acc += a * x[(size_t)s * 8 + k];
    }
    acc += __shfl_xor(acc, 32);
    if (lane < 32) xagg[(size_t)j * 40 + lane] = acc;
    else if (lane < 40) xagg[(size_t)j * 40 + lane] = x[(size_t)j * 8 + (lane - 32)];
}

// -------------------- aggregation, concat (H=4,C=64): ONE WAVE per node
// lane owns channels lane*4..+3 of the 256-wide concat row; head = lane>>4.
__global__ __launch_bounds__(256) void agg_concat_k(
    const bf16_t* __restrict__ h, const float* __restrict__ e_buf,
    const int* __restrict__ offs, const int* __restrict__ csr_src,
    const float* __restrict__ lin, const float* __restrict__ bgat,
    bf16_t* __restrict__ xb) {
    int wave = threadIdx.x >> 6, lane = threadIdx.x & 63;
    int j = blockIdx.x * 4 + wave;
    if (j >= N_NODES) return;
    int o0 = offs[j], deg = offs[j + 1] - o0;
    const float* eb = e_buf + (size_t)o0 * 4;
    float m = -3.4e38f, rd = 0.f;
    if (lane < 4) {
        for (int e = 0; e < deg; ++e) m = fmaxf(m, eb[e * 4 + lane]);
        float ss = 0.f;
        for (int e = 0; e < deg; ++e) ss += __expf(eb[e * 4 + lane] - m);
        rd = 1.f / (ss + 1e-16f);
    }
    int myh = lane >> 4;
    f32x4 acc = {};
    for (int e = 0; e < deg; ++e) {
        int s = csr_src[o0 + e];
        float av = (lane < 4) ? __expf(eb[e * 4 + lane] - m) * rd : 0.f;
        float a = __shfl(av, myh);
        bf16x4 v = *(const bf16x4*)&h[(size_t)s * 256 + lane * 4];
        #pragma unroll
        for (int i = 0; i < 4; ++i) acc[i] += a * (float)v[i];
    }
    f32x4 bg = *(const f32x4*)&bgat[lane * 4];
    f32x4 ln = *(const f32x4*)&lin[(size_t)j * 256 + lane * 4];
    bf16x4 o;
    #pragma unroll
    for (int i = 0; i < 4; ++i) o[i] = (bf16_t)fmaxf(acc[i] + bg[i] + ln[i], 0.f);
    *(bf16x4*)&xb[(size_t)j * 256 + lane * 4] = o;
}

// ----------- layer-3 x-aggregation (H=6 over x2 [N,256]): ONE WAVE per node
// lane owns channels lane*4..+3; 6 per-head f32x4 accumulators; att fused.
__global__ __launch_bounds__(256) void agg3_k(
    const bf16_t* __restrict__ x2, const float* __restrict__ e_buf,
    const int* __restrict__ offs, const int* __restrict__ csr_src,
    const int* __restrict__ csr_eid, bf16_t* __restrict__ xagg,
    float* __restrict__ att) {
    int wave = threadIdx.x >> 6, lane = threadIdx.x & 63;
    int j = blockIdx.x * 4 + wave;
    if (j >= N_NODES) return;
    int o0 = offs[j], deg = offs[j + 1] - o0;
    const float* eb = e_buf + (size_t)o0 * 6;
    float m = -3.4e38f, rd = 0.f;
    if (lane < 6) {
        for (int e = 0; e < deg; ++e) m = fmaxf(m, eb[e * 6 + lane]);
        float ss = 0.f;
        for (int e = 0; e < deg; ++e) ss += __expf(eb[e * 6 + lane] - m);
        rd = 1.f / (ss + 1e-16f);
    }
    f32x4 acc[6] = {};
    for (int e = 0; e < deg; ++e) {
        int s = csr_src[o0 + e];
        float av = (lane < 6) ? __expf(eb[e * 6 + lane] - m) * rd : 0.f;
        if (lane < 6) att[(size_t)csr_eid[o0 + e] * 6 + lane] = av;
        float a0 = __shfl(av, 0), a1 = __shfl(av, 1), a2 = __shfl(av, 2);
        float a3 = __shfl(av, 3), a4 = __shfl(av, 4), a5 = __shfl(av, 5);
        bf16x4 v = *(const bf16x4*)&x2[(size_t)s * 256 + lane * 4];
        float f0 = (float)v[0], f1 = (float)v[1], f2 = (float)v[2], f3 = (float)v[3];
        acc[0][0] += a0 * f0; acc[0][1] += a0 * f1; acc[0][2] += a0 * f2; acc[0][3] += a0 * f3;
        acc[1][0] += a1 * f0; acc[1][1] += a1 * f1; acc[1][2] += a1 * f2; acc[1][3] += a1 * f3;
        acc[2][0] += a2 * f0; acc[2][1] += a2 * f1; acc[2][2] += a2 * f2; acc[2][3] += a2 * f3;
        acc[3][0] += a3 * f0; acc[3][1] += a3 * f1; acc[3][2] += a3 * f2; acc[3][3] += a3 * f3;
        acc[4][0] += a4 * f0; acc[4][1] += a4 * f1; acc[4][2] += a4 * f2; acc[4][3] += a4 * f3;
        acc[5][0] += a5 * f0; acc[5][1] += a5 * f1; acc[5][2] += a5 * f2; acc[5][3] += a5 * f3;
    }
    bf16_t* row = xagg + (size_t)j * 1792;
    #pragma unroll
    for (int hh = 0; hh < 6; ++hh) {
        bf16x4 o;
        #pragma unroll
        for (int i = 0; i < 4; ++i) o[i] = (bf16_t)acc[hh][i];
        *(bf16x4*)&row[hh * 256 + lane * 4] = o;
    }
    *(bf16x4*)&row[1536 + lane * 4] = *(const bf16x4*)&x2[(size_t)j * 256 + lane * 4];
}

// ---------------------------------------------------------------- BatchNorm
__global__ void bn_stats_k(const float* __restrict__ y, float* __restrict__ sums, int N) {
    int c = threadIdx.x;  // 128
    float s = 0.f, q = 0.f;
    for (int r = blockIdx.x; r < N; r += gridDim.x) {
        float v = y[(size_t)r * 128 + c];
        s += v;
        q += v * v;
    }
    atomicAdd(&sums[c], s);
    atomicAdd(&sums[128 + c], q);
}
__global__ void bn_scale_k(const float* __restrict__ sums, const float* __restrict__ gamma,
                           const float* __restrict__ beta, float* __restrict__ scale,
                           float* __restrict__ shift, int N) {
    int c = threadIdx.x;
    float mu = sums[c] / (float)N;
    float var = fmaxf(sums[128 + c] / (float)N - mu * mu, 0.f);
    float inv = rsqrtf(var + 1e-5f) * gamma[c];
    scale[c] = inv;
    shift[c] = beta[c] - mu * inv;
}

// ---------------------------------------------------------------- max pool
__device__ __forceinline__ unsigned f2key(float f) {
    unsigned b = __float_as_uint(f);
    return (b & 0x80000000u) ? ~b : (b | 0x80000000u);
}
__global__ void pool_init_k(unsigned* __restrict__ pool_u) {
    int i = blockIdx.x * 256 + threadIdx.x;
    if (i < N_GRAPHS * 128) pool_u[i] = f2key(-3.402823466e38f * 2.0f);
}
__global__ void norm_pool_k(const float* __restrict__ y, const float* __restrict__ scale,
                            const float* __restrict__ shift, const int* __restrict__ batch,
                            unsigned* __restrict__ pool_u, int N) {
    int idx = blockIdx.x * 256 + threadIdx.x;
    if (idx >= N * 128) return;
    int n = idx >> 7, c = idx & 127;
    float v = y[idx] * scale[c] + shift[c];
    atomicMax(&pool_u[batch[n] * 128 + c], f2key(v));
}
__global__ void pool_write_k(const unsigned* __restrict__ pool_u, float* __restrict__ out) {
    int i = blockIdx.x * 256 + threadIdx.x;
    if (i < N_GRAPHS * 128) {
        unsigned u = pool_u[i];
        unsigned b = (u & 0x80000000u) ? (u & 0x7FFFFFFFu) : ~u;
        out[i] = __uint_as_float(b);
    }
}

// ================================================================ launcher
extern "C" void kernel_launch(void* const* d_in, const int* in_sizes, int n_in,
                              void* d_out, int out_size, void* d_ws, size_t ws_size,
                              hipStream_t stream) {
    const int N = N_NODES, E = N_EDGES;
    const float* x_ppi = (const float*)d_in[0];
    const int* edge = (const int*)d_in[1];
    const int* batch = (const int*)d_in[2];
    const float* W1 = (const float*)d_in[3];
    const float* a_src1 = (const float*)d_in[4];
    const float* a_dst1 = (const float*)d_in[5];
    const float* b_gat1 = (const float*)d_in[6];
    const float* lw1 = (const float*)d_in[7];
    const float* lb1 = (const float*)d_in[8];
    const float* W2 = (const float*)d_in[9];
    const float* a_src2 = (const float*)d_in[10];
    const float* a_dst2 = (const float*)d_in[11];
    const float* b_gat2 = (const float*)d_in[12];
    const float* lw2 = (const float*)d_in[13];
    const float* lb2 = (const float*)d_in[14];
    const float* W3 = (const float*)d_in[15];
    const float* a_src3 = (const float*)d_in[16];
    const float* a_dst3 = (const float*)d_in[17];
    const float* b_gat3 = (const float*)d_in[18];
    const float* lw3 = (const float*)d_in[19];
    const float* lb3 = (const float*)d_in[20];
    const float* bn_gamma = (const float*)d_in[21];
    const float* bn_beta = (const float*)d_in[22];

    const int* src = edge;
    const int* dst = edge + E;

    size_t off = 0;
    auto alloc = [&](size_t bytes) {
        size_t o = off;
        off = (off + bytes + 255) & ~(size_t)255;
        return o;
    };
    char* ws = (char*)d_ws;
    bf16_t* xb = (bf16_t*)(ws + alloc((size_t)N * 256 * 2));
    char* bigA = ws + alloc((size_t)N * 1792 * 2);
    bf16_t* xagg3 = (bf16_t*)bigA;
    bf16_t* hb = (bf16_t*)bigA;                                  // [N,256] bf16
    float* lin = (float*)(bigA + (((size_t)N * 256 * 2 + 255) & ~(size_t)255));
    float* xagg1 = (float*)(ws + alloc((size_t)N * 40 * 4));
    float* y = (float*)(ws + alloc((size_t)N * 128 * 4));
    float* as_ = (float*)(ws + alloc((size_t)N * 6 * 4));
    float* ad_ = (float*)(ws + alloc((size_t)N * 6 * 4));
    int* deg = (int*)(ws + alloc((size_t)(N + 1) * 4));
    int* offs = (int*)(ws + alloc((size_t)(N + 1) * 4));
    int* cursor = (int*)(ws + alloc((size_t)(N + 1) * 4));
    int* csr_src = (int*)(ws + alloc((size_t)E * 4));
    int* csr_dst = (int*)(ws + alloc((size_t)E * 4));
    int* csr_eid = (int*)(ws + alloc((size_t)E * 4));
    float* e_buf = (float*)(ws + alloc((size_t)E * 6 * 4));
    bf16_t* Bt2c = (bf16_t*)(ws + alloc((size_t)512 * 256 * 2));
    bf16_t* Bt3x = (bf16_t*)(ws + alloc((size_t)128 * 1792 * 2));
    float* B1 = (float*)(ws + alloc((size_t)40 * 256 * 4));
    float* bb1 = (float*)(ws + alloc(256 * 4));
    float* bb3 = (float*)(ws + alloc(128 * 4));
    float* WaT1 = (float*)(ws + alloc(64 * 4));
    float* WaT2 = (float*)(ws + alloc(2048 * 4));
    float* WaT3 = (float*)(ws + alloc(3072 * 4));
    float* bn_sums = (float*)(ws + alloc(256 * 4));
    float* bn_scale = (float*)(ws + alloc(128 * 4));
    float* bn_shift = (float*)(ws + alloc(128 * 4));
    unsigned* pool_u = (unsigned*)(ws + alloc((size_t)N_GRAPHS * 128 * 4));

    float* out_pool = (float*)d_out;
    float* out_att = (float*)d_out + N_GRAPHS * 128;

    // ---- CSR + weight prep (independent)
    hipMemsetAsync(deg, 0, (size_t)N * 4, stream);
    hist_k<<<(E + 255) / 256, 256, 0, stream>>>(dst, deg, E);
    scan_k<<<1, 1024, 0, stream>>>(deg, offs, cursor, N);
    scatter_k<<<(E + 255) / 256, 256, 0, stream>>>(src, dst, cursor, csr_src, csr_dst,
                                                   csr_eid, E);
    wt_k<<<dim3(8, 8), 256, 0, stream>>>(W2, Bt2c, 256, 256);
    wt_k<<<dim3(8, 8), 256, 0, stream>>>(lw2, Bt2c + 256 * 256, 256, 256);
    fold_k<<<1, 64, 0, stream>>>(W1, a_src1, a_dst1, WaT1, 8, 4, 64);
    fold_k<<<4, 64, 0, stream>>>(W2, a_src2, a_dst2, WaT2, 256, 4, 64);
    fold_k<<<4, 64, 0, stream>>>(W3, a_src3, a_dst3, WaT3, 256, 6, 128);
    b1prep_k<<<1, 256, 0, stream>>>(W1, lw1, b_gat1, lb1, B1, bb1);
    b3prep_k<<<128, 256, 0, stream>>>(W3, lw3, b_gat3, lb3, Bt3x, bb3);

    // ---- Layer 1: scores from x, edge scores, aggregate x, one fused GEMM
    scores1_k<<<(N + 255) / 256, 256, 0, stream>>>(x_ppi, WaT1, as_, ad_, N);
    escore_k<4><<<(E + 255) / 256, 256, 0, stream>>>(as_, ad_, csr_src, csr_dst, e_buf, E);
    agg1_k<<<(N + 3) / 4, 256, 0, stream>>>(x_ppi, e_buf, offs, csr_src, xagg1);
    gemm_k<bf16_t, true><<<dim3(4, 313), 256, 0, stream>>>(xagg1, B1, xb, bb1, N, 256, 40);

    // ---- Layer 2 (256 -> 256, dual-output bf16 MFMA GEMM)
    gemm_bf16_dual_k<<<dim3(4, 157), 256, 0, stream>>>(xb, Bt2c, hb, lin, lb2, N);
    scores_k<8><<<(N + 3) / 4, 256, 0, stream>>>(xb, WaT2, as_, ad_, N);
    escore_k<4><<<(E + 255) / 256, 256, 0, stream>>>(as_, ad_, csr_src, csr_dst, e_buf, E);
    agg_concat_k<<<(N + 3) / 4, 256, 0, stream>>>(hb, e_buf, offs, csr_src, lin, b_gat2, xb);

    // ---- Layer 3: scores, edge scores, aggregate x2 per head (+att), GEMM
    scores_k<12><<<(N + 3) / 4, 256, 0, stream>>>(xb, WaT3, as_, ad_, N);
    escore_k<6><<<(E + 255) / 256, 256, 0, stream>>>(as_, ad_, csr_src, csr_dst, e_buf, E);
    agg3_k<<<(N + 3) / 4, 256, 0, stream>>>(xb, e_buf, offs, csr_src, csr_eid, xagg3, out_att);
    gemm_bf16_k<float, true><<<dim3(1, 157), 256, 0, stream>>>(xagg3, Bt3x, y, bb3,
                                                               N, 128, 1792);

    // ---- BatchNorm (training stats, fused sum+sumsq pass)
    hipMemsetAsync(bn_sums, 0, 256 * 4, stream);
    bn_stats_k<<<160, 128, 0, stream>>>(y, bn_sums, N);
    bn_scale_k<<<1, 128, 0, stream>>>(bn_sums, bn_gamma, bn_beta, bn_scale, bn_shift, N);

    // ---- normalize + global max pool
    pool_init_k<<<(N_GRAPHS * 128 + 255) / 256, 256, 0, stream>>>(pool_u);
    norm_pool_k<<<((size_t)N * 128 + 255) / 256, 256, 0, stream>>>(y, bn_scale, bn_shift, batch,
                                                                   pool_u, N);
    pool_write_k<<<(N_GRAPHS * 128 + 255) / 256, 256, 0, stream>>>(pool_u, out_pool);
}

// Round 8
// 688.584 us; speedup vs baseline: 1.1379x; 1.0607x over previous
//
#include <hip/hip_runtime.h>
#include <hip/hip_bf16.h>
#include <math.h>

#define N_NODES 20000
#define N_EDGES 320000
#define N_GRAPHS 64

typedef __bf16 bf16_t;
typedef bf16_t bf16x8 __attribute__((ext_vector_type(8)));
typedef bf16_t bf16x4 __attribute__((ext_vector_type(4)));
typedef float f32x4 __attribute__((ext_vector_type(4)));

__device__ __forceinline__ float leaky02(float v) { return v > 0.f ? v : 0.2f * v; }

// ---------------------------------------------------------------- CSR build
__global__ void hist_k(const int* __restrict__ dst, int* __restrict__ deg, int E) {
    int e = blockIdx.x * 256 + threadIdx.x;
    if (e < E) atomicAdd(&deg[dst[e]], 1);
}

__global__ void scan_k(const int* __restrict__ deg, int* __restrict__ offs,
                       int* __restrict__ cursor, int n) {
    __shared__ int buf[1024];
    __shared__ int s_carry;
    int tid = threadIdx.x;
    if (tid == 0) s_carry = 0;
    __syncthreads();
    for (int base = 0; base < n; base += 1024) {
        int carry = s_carry;
        int i = base + tid;
        int v = (i < n) ? deg[i] : 0;
        buf[tid] = v;
        __syncthreads();
        for (int off = 1; off < 1024; off <<= 1) {
            int t = (tid >= off) ? buf[tid - off] : 0;
            __syncthreads();
            buf[tid] += t;
            __syncthreads();
        }
        int incl = buf[tid];
        if (i < n) { int ex = carry + incl - v; offs[i] = ex; cursor[i] = ex; }
        if (tid == 1023) s_carry = carry + incl;
        __syncthreads();
    }
    if (tid == 0) offs[n] = s_carry;
}

__global__ void scatter_k(const int* __restrict__ src, const int* __restrict__ dst,
                          int* __restrict__ cursor, int* __restrict__ csr_src,
                          int* __restrict__ csr_dst, int* __restrict__ csr_eid, int E) {
    int e = blockIdx.x * 256 + threadIdx.x;
    if (e < E) {
        int d = dst[e];
        int p = atomicAdd(&cursor[d], 1);
        csr_src[p] = src[e];
        csr_dst[p] = d;
        csr_eid[p] = e;
    }
}

// --------------------------------------------- weight transpose + bf16 cast
__global__ __launch_bounds__(256) void wt_k(const float* __restrict__ W,
                                            bf16_t* __restrict__ Bt, int K, int N) {
    __shared__ float t[32][33];
    int k0 = blockIdx.y * 32, n0 = blockIdx.x * 32;
    int tx = threadIdx.x & 31, ty = threadIdx.x >> 5;
    for (int i = ty; i < 32; i += 8) t[i][tx] = W[(size_t)(k0 + i) * N + n0 + tx];
    __syncthreads();
    for (int i = ty; i < 32; i += 8)
        Bt[(size_t)(n0 + i) * K + k0 + tx] = (bf16_t)t[tx][i];
}

// ------------------------------------- fold attention vectors into weights
__global__ void fold_k(const float* __restrict__ W, const float* __restrict__ a_s,
                       const float* __restrict__ a_d, float* __restrict__ WaT,
                       int K, int H, int C) {
    int k = blockIdx.x * 64 + threadIdx.x;
    if (k >= K) return;
    int HC = H * C;
    for (int h = 0; h < H; ++h) {
        float s = 0.f, d = 0.f;
        for (int c = 0; c < C; ++c) {
            float w = W[(size_t)k * HC + h * C + c];
            s += w * a_s[h * C + c];
            d += w * a_d[h * C + c];
        }
        WaT[h * K + k] = s;
        WaT[(H + h) * K + k] = d;
    }
}

// --------------- prep: layer-1 fused Bt [256][64] bf16 (K padded 40->64)
__global__ void b1prep_k(const float* __restrict__ W1, const float* __restrict__ lw1,
                         const float* __restrict__ bg, const float* __restrict__ lb,
                         bf16_t* __restrict__ Bt, float* __restrict__ bb1) {
    int t = threadIdx.x;  // 256, one block; t = output col n
    for (int k = 0; k < 64; ++k) {
        float v = 0.f;
        if (k < 32) {
            int h = k >> 3, kk = k & 7;
            v = ((t >> 6) == h) ? W1[kk * 256 + t] : 0.f;
        } else if (k < 40) {
            v = lw1[(k - 32) * 256 + t];
        }
        Bt[(size_t)t * 64 + k] = (bf16_t)v;
    }
    bb1[t] = bg[t] + lb[t];
}

// ----------------------- prep: layer-3 fused Bt [128][1792] bf16
__global__ void b3prep_k(const float* __restrict__ W3, const float* __restrict__ lw3,
                         const float* __restrict__ bg, const float* __restrict__ lb,
                         bf16_t* __restrict__ Bt, float* __restrict__ bb) {
    int c = blockIdx.x;  // 0..127
    for (int idx = threadIdx.x; idx < 1792; idx += 256) {
        float v;
        if (idx < 1536) {
            int h = idx >> 8, k = idx & 255;
            v = W3[(size_t)k * 768 + h * 128 + c] * (1.f / 6.f);
        } else {
            int k = idx - 1536;
            v = lw3[(size_t)k * 128 + c];
        }
        Bt[(size_t)c * 1792 + idx] = (bf16_t)v;
    }
    if (threadIdx.x == 0) bb[c] = bg[c] + lb[c];
}

// ------------------------------------------------------------ bf16 MFMA GEMM
template <typename OUT, bool RELU>
__global__ __launch_bounds__(256) void gemm_bf16_k(
    const bf16_t* __restrict__ A, const bf16_t* __restrict__ Bt,
    OUT* __restrict__ C, const float* __restrict__ bias, int M, int N, int K) {
    __shared__ bf16_t As[128][40];
    __shared__ bf16_t Bs[128][40];
    int tid = threadIdx.x;
    int row0 = blockIdx.y * 128, col0 = blockIdx.x * 128;
    int wave = tid >> 6, lane = tid & 63, quad = lane >> 4, l16 = lane & 15;
    int wm = wave >> 1, wn = wave & 1;
    f32x4 acc[4][4] = {};
    int sr = tid >> 2;
    int sc = (tid & 3) * 8;
    for (int k0 = 0; k0 < K; k0 += 32) {
        #pragma unroll
        for (int half = 0; half < 2; ++half) {
            int r = sr + half * 64;
            int gm = row0 + r;
            bf16x8 v = {};
            if (gm < M) v = *(const bf16x8*)&A[(size_t)gm * K + k0 + sc];
            *(bf16x8*)&As[r][sc] = v;
            int gn = col0 + r;
            bf16x8 w = {};
            if (gn < N) w = *(const bf16x8*)&Bt[(size_t)gn * K + k0 + sc];
            *(bf16x8*)&Bs[r][sc] = w;
        }
        __syncthreads();
        bf16x8 af[4], bfr[4];
        #pragma unroll
        for (int i = 0; i < 4; ++i) {
            af[i] = *(const bf16x8*)&As[wm * 64 + i * 16 + l16][quad * 8];
            bfr[i] = *(const bf16x8*)&Bs[wn * 64 + i * 16 + l16][quad * 8];
        }
        #pragma unroll
        for (int i = 0; i < 4; ++i)
            #pragma unroll
            for (int j = 0; j < 4; ++j)
                acc[i][j] = __builtin_amdgcn_mfma_f32_16x16x32_bf16(af[i], bfr[j],
                                                                   acc[i][j], 0, 0, 0);
        __syncthreads();
    }
    #pragma unroll
    for (int i = 0; i < 4; ++i) {
        int base_m = row0 + wm * 64 + i * 16 + quad * 4;
        #pragma unroll
        for (int j = 0; j < 4; ++j) {
            int gn = col0 + wn * 64 + j * 16 + l16;
            float bv = bias ? bias[gn] : 0.f;
            #pragma unroll
            for (int r = 0; r < 4; ++r) {
                int gm = base_m + r;
                if (gm < M) {
                    float v = acc[i][j][r] + bv;
                    if (RELU) v = fmaxf(v, 0.f);
                    C[(size_t)gm * N + gn] = (OUT)v;
                }
            }
        }
    }
}

// ------------------------- layer-2 dual GEMM: [Wt2 ‖ lwt2], K=256, N=512
__global__ __launch_bounds__(256) void gemm_bf16_dual_k(
    const bf16_t* __restrict__ A, const bf16_t* __restrict__ Bt,
    bf16_t* __restrict__ Ch, float* __restrict__ Cl,
    const float* __restrict__ lbias, int M) {
    const int K = 256;
    __shared__ bf16_t As[128][40];
    __shared__ bf16_t Bs[128][40];
    int tid = threadIdx.x;
    int row0 = blockIdx.y * 128, col0 = blockIdx.x * 128;
    int wave = tid >> 6, lane = tid & 63, quad = lane >> 4, l16 = lane & 15;
    int wm = wave >> 1, wn = wave & 1;
    f32x4 acc[4][4] = {};
    int sr = tid >> 2;
    int sc = (tid & 3) * 8;
    for (int k0 = 0; k0 < K; k0 += 32) {
        #pragma unroll
        for (int half = 0; half < 2; ++half) {
            int r = sr + half * 64;
            int gm = row0 + r;
            bf16x8 v = {};
            if (gm < M) v = *(const bf16x8*)&A[(size_t)gm * K + k0 + sc];
            *(bf16x8*)&As[r][sc] = v;
            int gn = col0 + r;
            bf16x8 w = *(const bf16x8*)&Bt[(size_t)gn * K + k0 + sc];
            *(bf16x8*)&Bs[r][sc] = w;
        }
        __syncthreads();
        bf16x8 af[4], bfr[4];
        #pragma unroll
        for (int i = 0; i < 4; ++i) {
            af[i] = *(const bf16x8*)&As[wm * 64 + i * 16 + l16][quad * 8];
            bfr[i] = *(const bf16x8*)&Bs[wn * 64 + i * 16 + l16][quad * 8];
        }
        #pragma unroll
        for (int i = 0; i < 4; ++i)
            #pragma unroll
            for (int j = 0; j < 4; ++j)
                acc[i][j] = __builtin_amdgcn_mfma_f32_16x16x32_bf16(af[i], bfr[j],
                                                                   acc[i][j], 0, 0, 0);
        __syncthreads();
    }
    #pragma unroll
    for (int i = 0; i < 4; ++i) {
        int base_m = row0 + wm * 64 + i * 16 + quad * 4;
        #pragma unroll
        for (int j = 0; j < 4; ++j) {
            int gn = col0 + wn * 64 + j * 16 + l16;
            float bv = (gn >= 256) ? lbias[gn - 256] : 0.f;
            #pragma unroll
            for (int r = 0; r < 4; ++r) {
                int gm = base_m + r;
                if (gm < M) {
                    float v = acc[i][j][r] + bv;
                    if (gn < 256) Ch[(size_t)gm * 256 + gn] = (bf16_t)v;
                    else Cl[(size_t)gm * 256 + (gn - 256)] = v;
                }
            }
        }
    }
}

// -------------------------------------------- attention scores via folded W
__global__ void scores1_k(const float* __restrict__ x, const float* __restrict__ WaT,
                          float* __restrict__ as_, float* __restrict__ ad_, int N) {
    int j = blockIdx.x * 256 + threadIdx.x;
    if (j >= N) return;
    float xr[8];
    #pragma unroll
    for (int k = 0; k < 8; ++k) xr[k] = x[(size_t)j * 8 + k];
    #pragma unroll
    for (int t = 0; t < 8; ++t) {
        float s = 0.f;
        #pragma unroll
        for (int k = 0; k < 8; ++k) s += xr[k] * WaT[t * 8 + k];
        if (t < 4) as_[j * 4 + t] = s;
        else ad_[j * 4 + (t - 4)] = s;
    }
}

template <int TWOH>
__global__ __launch_bounds__(256) void scores_k(const bf16_t* __restrict__ xb,
                                                const float* __restrict__ WaT,
                                                float* __restrict__ as_,
                                                float* __restrict__ ad_, int N) {
    int tid = threadIdx.x, wave = tid >> 6, lane = tid & 63;
    int j = blockIdx.x * 4 + wave;
    bf16x4 v = {};
    if (j < N) v = *(const bf16x4*)&xb[(size_t)j * 256 + lane * 4];
    float x0 = (float)v[0], x1 = (float)v[1], x2 = (float)v[2], x3 = (float)v[3];
    float acc[TWOH];
    #pragma unroll
    for (int t = 0; t < TWOH; ++t) {
        f32x4 w = *(const f32x4*)&WaT[t * 256 + lane * 4];
        acc[t] = x0 * w[0] + x1 * w[1] + x2 * w[2] + x3 * w[3];
    }
    #pragma unroll
    for (int off = 32; off; off >>= 1)
        #pragma unroll
        for (int t = 0; t < TWOH; ++t) acc[t] += __shfl_xor(acc[t], off);
    if (lane == 0 && j < N) {
        const int H = TWOH / 2;
        #pragma unroll
        for (int t = 0; t < H; ++t) as_[j * H + t] = acc[t];
        #pragma unroll
        for (int t = 0; t < H; ++t) ad_[j * H + t] = acc[H + t];
    }
}

// ----------------------------- per-edge scores in CSR order, stride S
template <int H, int S>
__global__ void escore_k(const float* __restrict__ as_, const float* __restrict__ ad_,
                         const int* __restrict__ csr_src, const int* __restrict__ csr_dst,
                         float* __restrict__ e_buf, int E) {
    int p = blockIdx.x * 256 + threadIdx.x;
    if (p >= E) return;
    int s = csr_src[p], j = csr_dst[p];
    #pragma unroll
    for (int h = 0; h < H; ++h)
        e_buf[(size_t)p * S + h] = leaky02(as_[s * H + h] + ad_[j * H + h]);
}

// -------- per-node softmax stats: wave per node, log-step shuffle reductions
// m -> m_buf[j*H+h], 1/denom -> rd_buf[j*H+h]
template <int H, int S>
__global__ __launch_bounds__(256) void softstat_k(
    const float* __restrict__ e_buf, const int* __restrict__ offs,
    float* __restrict__ m_buf, float* __restrict__ rd_buf, int N) {
    const int EPW = 64 / S;
    int wave = threadIdx.x >> 6, lane = threadIdx.x & 63;
    int j = blockIdx.x * 4 + wave;
    if (j >= N) return;
    int o0 = offs[j], deg = offs[j + 1] - o0;
    const float* eb = e_buf + (size_t)o0 * S;
    int slot = lane & (S - 1), erel = lane / S;
    float m = -3.4e38f;
    for (int e0 = 0; e0 < deg; e0 += EPW) {
        int e = e0 + erel;
        float v = -3.4e38f;
        if (e < deg && slot < H) v = eb[e * S + slot];
        m = fmaxf(m, v);
    }
    #pragma unroll
    for (int mask = S; mask < 64; mask <<= 1) m = fmaxf(m, __shfl_xor(m, mask));
    float ss = 0.f;
    for (int e0 = 0; e0 < deg; e0 += EPW) {
        int e = e0 + erel;
        if (e < deg && slot < H) ss += __expf(eb[e * S + slot] - m);
    }
    #pragma unroll
    for (int mask = S; mask < 64; mask <<= 1) ss += __shfl_xor(ss, mask);
    if (lane < H) {
        m_buf[j * H + lane] = m;
        rd_buf[j * H + lane] = 1.f / (ss + 1e-16f);
    }
}

// -------- edge-parallel alpha: e_buf := exp(e_buf - m)*rd, in place (+att)
template <int H, int S, bool ATT>
__global__ void alpha_k(float* __restrict__ e_buf, const float* __restrict__ m_buf,
                        const float* __restrict__ rd_buf, const int* __restrict__ csr_dst,
                        const int* __restrict__ csr_eid, float* __restrict__ att, int E) {
    int p = blockIdx.x * 256 + threadIdx.x;
    if (p >= E) return;
    int j = csr_dst[p];
    int eid = ATT ? csr_eid[p] : 0;
    #pragma unroll
    for (int h = 0; h < H; ++h) {
        float a = __expf(e_buf[(size_t)p * S + h] - m_buf[j * H + h]) * rd_buf[j * H + h];
        e_buf[(size_t)p * S + h] = a;
        if (ATT) att[(size_t)eid * 6 + h] = a;
    }
}

// -------------------------- layer-1 x-aggregation (H=4, x 8-wide) -> [N,64]
__global__ __launch_bounds__(256) void agg1_k(
    const float* __restrict__ x, const float* __restrict__ alpha,
    const int* __restrict__ offs, const int* __restrict__ csr_src,
    bf16_t* __restrict__ xagg) {
    int wave = threadIdx.x >> 6, lane = threadIdx.x & 63;
    int j = blockIdx.x * 4 + wave;
    if (j >= N_NODES) return;
    int o0 = offs[j], deg = offs[j + 1] - o0;
    const float* ab = alpha + (size_t)o0 * 4;
    int half = lane >> 5, l = lane & 31, h = l >> 3, k = l & 7;
    float acc = 0.f;
    for (int e = half; e < deg; e += 2) {
        int s = csr_src[o0 + e];
        acc += ab[e * 4 + h] * x[(size_t)s * 8 + k];
    }
    acc += __shfl_xor(acc, 32);
    bf16_t o;
    if (lane < 32) o = (bf16_t)acc;
    else if (lane < 40) o = (bf16_t)x[(size_t)j * 8 + (lane - 32)];
    else o = (bf16_t)0.f;
    xagg[(size_t)j * 64 + lane] = o;
}

// -------------------- aggregation, concat (H=4,C=64): wave per node
__global__ __launch_bounds__(256) void agg_concat_k(
    const bf16_t* __restrict__ h, const float* __restrict__ alpha,
    const int* __restrict__ offs, const int* __restrict__ csr_src,
    const float* __restrict__ lin, const float* __restrict__ bgat,
    bf16_t* __restrict__ xb) {
    int wave = threadIdx.x >> 6, lane = threadIdx.x & 63;
    int j = blockIdx.x * 4 + wave;
    if (j >= N_NODES) return;
    int o0 = offs[j], deg = offs[j + 1] - o0;
    const float* ab = alpha + (size_t)o0 * 4;
    int myh = lane >> 4;
    f32x4 acc = {};
    int e = 0;
    for (; e + 1 < deg; e += 2) {
        int s0 = csr_src[o0 + e], s1 = csr_src[o0 + e + 1];
        float av0 = (lane < 4) ? ab[e * 4 + lane] : 0.f;
        float av1 = (lane < 4) ? ab[(e + 1) * 4 + lane] : 0.f;
        float a0 = __shfl(av0, myh), a1 = __shfl(av1, myh);
        bf16x4 v0 = *(const bf16x4*)&h[(size_t)s0 * 256 + lane * 4];
        bf16x4 v1 = *(const bf16x4*)&h[(size_t)s1 * 256 + lane * 4];
        #pragma unroll
        for (int i = 0; i < 4; ++i) acc[i] += a0 * (float)v0[i];
        #pragma unroll
        for (int i = 0; i < 4; ++i) acc[i] += a1 * (float)v1[i];
    }
    if (e < deg) {
        int s0 = csr_src[o0 + e];
        float av0 = (lane < 4) ? ab[e * 4 + lane] : 0.f;
        float a0 = __shfl(av0, myh);
        bf16x4 v0 = *(const bf16x4*)&h[(size_t)s0 * 256 + lane * 4];
        #pragma unroll
        for (int i = 0; i < 4; ++i) acc[i] += a0 * (float)v0[i];
    }
    f32x4 bg = *(const f32x4*)&bgat[lane * 4];
    f32x4 ln = *(const f32x4*)&lin[(size_t)j * 256 + lane * 4];
    bf16x4 o;
    #pragma unroll
    for (int i = 0; i < 4; ++i) o[i] = (bf16_t)fmaxf(acc[i] + bg[i] + ln[i], 0.f);
    *(bf16x4*)&xb[(size_t)j * 256 + lane * 4] = o;
}

// ----------- layer-3 x-aggregation: TWO waves per node (3 heads each)
__global__ __launch_bounds__(256) void agg3_k(
    const bf16_t* __restrict__ x2, const float* __restrict__ alpha,
    const int* __restrict__ offs, const int* __restrict__ csr_src,
    bf16_t* __restrict__ xagg, int N) {
    int wid = threadIdx.x >> 6, lane = threadIdx.x & 63;
    int j = blockIdx.x * 2 + (wid >> 1);
    int hg = wid & 1;  // head group: heads hg*3 .. hg*3+2
    if (j >= N) return;
    int o0 = offs[j], deg = offs[j + 1] - o0;
    const float* ab = alpha + (size_t)o0 * 8;
    f32x4 acc[3] = {};
    int e = 0;
    for (; e + 1 < deg; e += 2) {
        int s0 = csr_src[o0 + e], s1 = csr_src[o0 + e + 1];
        float av0 = (lane < 3) ? ab[e * 8 + hg * 3 + lane] : 0.f;
        float av1 = (lane < 3) ? ab[(e + 1) * 8 + hg * 3 + lane] : 0.f;
        bf16x4 v0 = *(const bf16x4*)&x2[(size_t)s0 * 256 + lane * 4];
        bf16x4 v1 = *(const bf16x4*)&x2[(size_t)s1 * 256 + lane * 4];
        float f00 = (float)v0[0], f01 = (float)v0[1], f02 = (float)v0[2], f03 = (float)v0[3];
        float f10 = (float)v1[0], f11 = (float)v1[1], f12 = (float)v1[2], f13 = (float)v1[3];
        #pragma unroll
        for (int hh = 0; hh < 3; ++hh) {
            float a0 = __shfl(av0, hh), a1 = __shfl(av1, hh);
            acc[hh][0] += a0 * f00 + a1 * f10;
            acc[hh][1] += a0 * f01 + a1 * f11;
            acc[hh][2] += a0 * f02 + a1 * f12;
            acc[hh][3] += a0 * f03 + a1 * f13;
        }
    }
    if (e < deg) {
        int s0 = csr_src[o0 + e];
        float av0 = (lane < 3) ? ab[e * 8 + hg * 3 + lane] : 0.f;
        bf16x4 v0 = *(const bf16x4*)&x2[(size_t)s0 * 256 + lane * 4];
        float f00 = (float)v0[0], f01 = (float)v0[1], f02 = (float)v0[2], f03 = (float)v0[3];
        #pragma unroll
        for (int hh = 0; hh < 3; ++hh) {
            float a0 = __shfl(av0, hh);
            acc[hh][0] += a0 * f00;
            acc[hh][1] += a0 * f01;
            acc[hh][2] += a0 * f02;
            acc[hh][3] += a0 * f03;
        }
    }
    bf16_t* row = xagg + (size_t)j * 1792;
    #pragma unroll
    for (int hh = 0; hh < 3; ++hh) {
        bf16x4 o;
        #pragma unroll
        for (int i = 0; i < 4; ++i) o[i] = (bf16_t)acc[hh][i];
        *(bf16x4*)&row[(hg * 3 + hh) * 256 + lane * 4] = o;
    }
    if (hg == 1)
        *(bf16x4*)&row[1536 + lane * 4] = *(const bf16x4*)&x2[(size_t)j * 256 + lane * 4];
}

// ---------------------------------------------------------------- BatchNorm
__global__ void bn_stats_k(const float* __restrict__ y, float* __restrict__ sums, int N) {
    int c = threadIdx.x;  // 128
    float s = 0.f, q = 0.f;
    for (int r = blockIdx.x; r < N; r += gridDim.x) {
        float v = y[(size_t)r * 128 + c];
        s += v;
        q += v * v;
    }
    atomicAdd(&sums[c], s);
    atomicAdd(&sums[128 + c], q);
}

__device__ __forceinline__ unsigned f2key(float f) {
    unsigned b = __float_as_uint(f);
    return (b & 0x80000000u) ? ~b : (b | 0x80000000u);
}

// bn scale/shift (block 0) + pool init (blocks 1..32)
__global__ void bn_scale_pool_k(const float* __restrict__ sums,
                                const float* __restrict__ gamma,
                                const float* __restrict__ beta, float* __restrict__ scale,
                                float* __restrict__ shift, unsigned* __restrict__ pool_u,
                                int N) {
    if (blockIdx.x == 0) {
        int c = threadIdx.x;
        if (c < 128) {
            float mu = sums[c] / (float)N;
            float var = fmaxf(sums[128 + c] / (float)N - mu * mu, 0.f);
            float inv = rsqrtf(var + 1e-5f) * gamma[c];
            scale[c] = inv;
            shift[c] = beta[c] - mu * inv;
        }
    } else {
        int i = (blockIdx.x - 1) * 256 + threadIdx.x;
        if (i < N_GRAPHS * 128) pool_u[i] = f2key(-3.402823466e38f * 2.0f);
    }
}

__global__ void norm_pool_k(const float* __restrict__ y, const float* __restrict__ scale,
                            const float* __restrict__ shift, const int* __restrict__ batch,
                            unsigned* __restrict__ pool_u, int N) {
    int idx = blockIdx.x * 256 + threadIdx.x;
    if (idx >= N * 128) return;
    int n = idx >> 7, c = idx & 127;
    float v = y[idx] * scale[c] + shift[c];
    atomicMax(&pool_u[batch[n] * 128 + c], f2key(v));
}
__global__ void pool_write_k(const unsigned* __restrict__ pool_u, float* __restrict__ out) {
    int i = blockIdx.x * 256 + threadIdx.x;
    if (i < N_GRAPHS * 128) {
        unsigned u = pool_u[i];
        unsigned b = (u & 0x80000000u) ? (u & 0x7FFFFFFFu) : ~u;
        out[i] = __uint_as_float(b);
    }
}

// ================================================================ launcher
extern "C" void kernel_launch(void* const* d_in, const int* in_sizes, int n_in,
                              void* d_out, int out_size, void* d_ws, size_t ws_size,
                              hipStream_t stream) {
    const int N = N_NODES, E = N_EDGES;
    const float* x_ppi = (const float*)d_in[0];
    const int* edge = (const int*)d_in[1];
    const int* batch = (const int*)d_in[2];
    const float* W1 = (const float*)d_in[3];
    const float* a_src1 = (const float*)d_in[4];
    const float* a_dst1 = (const float*)d_in[5];
    const float* b_gat1 = (const float*)d_in[6];
    const float* lw1 = (const float*)d_in[7];
    const float* lb1 = (const float*)d_in[8];
    const float* W2 = (const float*)d_in[9];
    const float* a_src2 = (const float*)d_in[10];
    const float* a_dst2 = (const float*)d_in[11];
    const float* b_gat2 = (const float*)d_in[12];
    const float* lw2 = (const float*)d_in[13];
    const float* lb2 = (const float*)d_in[14];
    const float* W3 = (const float*)d_in[15];
    const float* a_src3 = (const float*)d_in[16];
    const float* a_dst3 = (const float*)d_in[17];
    const float* b_gat3 = (const float*)d_in[18];
    const float* lw3 = (const float*)d_in[19];
    const float* lb3 = (const float*)d_in[20];
    const float* bn_gamma = (const float*)d_in[21];
    const float* bn_beta = (const float*)d_in[22];

    const int* src = edge;
    const int* dst = edge + E;

    size_t off = 0;
    auto alloc = [&](size_t bytes) {
        size_t o = off;
        off = (off + bytes + 255) & ~(size_t)255;
        return o;
    };
    char* ws = (char*)d_ws;
    bf16_t* xb = (bf16_t*)(ws + alloc((size_t)N * 256 * 2));
    char* bigA = ws + alloc((size_t)N * 1792 * 2);
    bf16_t* xagg3 = (bf16_t*)bigA;
    bf16_t* hb = (bf16_t*)bigA;                                  // [N,256] bf16
    float* lin = (float*)(bigA + (((size_t)N * 256 * 2 + 255) & ~(size_t)255));
    bf16_t* xagg1 = (bf16_t*)(ws + alloc((size_t)N * 64 * 2));
    float* y = (float*)(ws + alloc((size_t)N * 128 * 4));
    float* as_ = (float*)(ws + alloc((size_t)N * 6 * 4));   // reused as m_buf
    float* ad_ = (float*)(ws + alloc((size_t)N * 6 * 4));   // reused as rd_buf
    int* deg = (int*)(ws + alloc((size_t)(N + 1) * 4));
    int* offs = (int*)(ws + alloc((size_t)(N + 1) * 4));
    int* cursor = (int*)(ws + alloc((size_t)(N + 1) * 4));
    int* csr_src = (int*)(ws + alloc((size_t)E * 4));
    int* csr_dst = (int*)(ws + alloc((size_t)E * 4));
    int* csr_eid = (int*)(ws + alloc((size_t)E * 4));
    float* e_buf = (float*)(ws + alloc((size_t)E * 8 * 4));
    bf16_t* Bt2c = (bf16_t*)(ws + alloc((size_t)512 * 256 * 2));
    bf16_t* Bt3x = (bf16_t*)(ws + alloc((size_t)128 * 1792 * 2));
    bf16_t* Bt1 = (bf16_t*)(ws + alloc((size_t)256 * 64 * 2));
    float* bb1 = (float*)(ws + alloc(256 * 4));
    float* bb3 = (float*)(ws + alloc(128 * 4));
    float* WaT1 = (float*)(ws + alloc(64 * 4));
    float* WaT2 = (float*)(ws + alloc(2048 * 4));
    float* WaT3 = (float*)(ws + alloc(3072 * 4));
    float* bn_sums = (float*)(ws + alloc(256 * 4));
    float* bn_scale = (float*)(ws + alloc(128 * 4));
    float* bn_shift = (float*)(ws + alloc(128 * 4));
    unsigned* pool_u = (unsigned*)(ws + alloc((size_t)N_GRAPHS * 128 * 4));

    float* out_pool = (float*)d_out;
    float* out_att = (float*)d_out + N_GRAPHS * 128;

    int egrid = (E + 255) / 256;
    int ngrid4 = (N + 3) / 4;

    // ---- CSR + weight prep (independent)
    hipMemsetAsync(deg, 0, (size_t)N * 4, stream);
    hist_k<<<egrid, 256, 0, stream>>>(dst, deg, E);
    scan_k<<<1, 1024, 0, stream>>>(deg, offs, cursor, N);
    scatter_k<<<egrid, 256, 0, stream>>>(src, dst, cursor, csr_src, csr_dst, csr_eid, E);
    wt_k<<<dim3(8, 8), 256, 0, stream>>>(W2, Bt2c, 256, 256);
    wt_k<<<dim3(8, 8), 256, 0, stream>>>(lw2, Bt2c + 256 * 256, 256, 256);
    fold_k<<<1, 64, 0, stream>>>(W1, a_src1, a_dst1, WaT1, 8, 4, 64);
    fold_k<<<4, 64, 0, stream>>>(W2, a_src2, a_dst2, WaT2, 256, 4, 64);
    fold_k<<<4, 64, 0, stream>>>(W3, a_src3, a_dst3, WaT3, 256, 6, 128);
    b1prep_k<<<1, 256, 0, stream>>>(W1, lw1, b_gat1, lb1, Bt1, bb1);
    b3prep_k<<<128, 256, 0, stream>>>(W3, lw3, b_gat3, lb3, Bt3x, bb3);

    // ---- Layer 1
    scores1_k<<<(N + 255) / 256, 256, 0, stream>>>(x_ppi, WaT1, as_, ad_, N);
    escore_k<4, 4><<<egrid, 256, 0, stream>>>(as_, ad_, csr_src, csr_dst, e_buf, E);
    softstat_k<4, 4><<<ngrid4, 256, 0, stream>>>(e_buf, offs, as_, ad_, N);
    alpha_k<4, 4, false><<<egrid, 256, 0, stream>>>(e_buf, as_, ad_, csr_dst, nullptr,
                                                    nullptr, E);
    agg1_k<<<ngrid4, 256, 0, stream>>>(x_ppi, e_buf, offs, csr_src, xagg1);
    gemm_bf16_k<bf16_t, true><<<dim3(2, 157), 256, 0, stream>>>(xagg1, Bt1, xb, bb1,
                                                                N, 256, 64);

    // ---- Layer 2
    gemm_bf16_dual_k<<<dim3(4, 157), 256, 0, stream>>>(xb, Bt2c, hb, lin, lb2, N);
    scores_k<8><<<ngrid4, 256, 0, stream>>>(xb, WaT2, as_, ad_, N);
    escore_k<4, 4><<<egrid, 256, 0, stream>>>(as_, ad_, csr_src, csr_dst, e_buf, E);
    softstat_k<4, 4><<<ngrid4, 256, 0, stream>>>(e_buf, offs, as_, ad_, N);
    alpha_k<4, 4, false><<<egrid, 256, 0, stream>>>(e_buf, as_, ad_, csr_dst, nullptr,
                                                    nullptr, E);
    agg_concat_k<<<ngrid4, 256, 0, stream>>>(hb, e_buf, offs, csr_src, lin, b_gat2, xb);

    // ---- Layer 3
    scores_k<12><<<ngrid4, 256, 0, stream>>>(xb, WaT3, as_, ad_, N);
    escore_k<6, 8><<<egrid, 256, 0, stream>>>(as_, ad_, csr_src, csr_dst, e_buf, E);
    softstat_k<6, 8><<<ngrid4, 256, 0, stream>>>(e_buf, offs, as_, ad_, N);
    alpha_k<6, 8, true><<<egrid, 256, 0, stream>>>(e_buf, as_, ad_, csr_dst, csr_eid,
                                                   out_att, E);
    agg3_k<<<(N + 1) / 2, 256, 0, stream>>>(xb, e_buf, offs, csr_src, xagg3, N);
    gemm_bf16_k<float, true><<<dim3(1, 157), 256, 0, stream>>>(xagg3, Bt3x, y, bb3,
                                                               N, 128, 1792);

    // ---- BatchNorm + pool
    hipMemsetAsync(bn_sums, 0, 256 * 4, stream);
    bn_stats_k<<<160, 128, 0, stream>>>(y, bn_sums, N);
    bn_scale_pool_k<<<33, 256, 0, stream>>>(bn_sums, bn_gamma, bn_beta, bn_scale, bn_shift,
                                            pool_u, N);
    norm_pool_k<<<((size_t)N * 128 + 255) / 256, 256, 0, stream>>>(y, bn_scale, bn_shift,
                                                                   batch, pool_u, N);
    pool_write_k<<<(N_GRAPHS * 128 + 255) / 256, 256, 0, stream>>>(pool_u, out_pool);
}